// Round 3
// baseline (951.040 us; speedup 1.0000x reference)
//
#include <hip/hip_runtime.h>

#define NNODES 49152
#define NB 4
#define NE 393216
#define MTOT (NB*NNODES)
#define EPS 1e-5f

typedef __attribute__((ext_vector_type(8))) short s8v;   // 8 x bf16 (raw)
typedef __attribute__((ext_vector_type(4))) float f32x4;

__device__ inline float b2f(ushort u){ union{uint i; float f;} v; v.i = ((uint)u)<<16; return v.f; }
__device__ inline ushort f2b(float f){ union{float f; uint i;} v; v.f=f; uint r = v.i + 0x7fff + ((v.i>>16)&1); return (ushort)(r>>16); }

// ---------------- setup kernels ----------------
__global__ __launch_bounds__(256) void k_deg_cnt(const int* __restrict__ row,
    const float* __restrict__ w, float* __restrict__ deg, int* __restrict__ cnt)
{
    int e = blockIdx.x*256 + threadIdx.x;
    if (e >= NE) return;
    int r = row[e];
    atomicAdd(&deg[r], w[e]);
    atomicAdd(&cnt[r], 1);
}

__global__ __launch_bounds__(256) void k_dinv(const float* __restrict__ deg, float* __restrict__ dinv)
{
    int i = blockIdx.x*256 + threadIdx.x;
    if (i >= NNODES) return;
    float d = deg[i];
    dinv[i] = (d > 0.0f) ? rsqrtf(fmaxf(d, EPS)) : 0.0f;
}

__global__ __launch_bounds__(1024) void k_scan(const int* __restrict__ cnt, int* __restrict__ rowptr)
{
    __shared__ int ssum[1024];
    const int CH = NNODES/1024; // 48
    int t = threadIdx.x;
    int base = t*CH;
    int loc[CH];
    int s = 0;
    #pragma unroll
    for (int i = 0; i < CH; ++i) { loc[i] = s; s += cnt[base+i]; }
    ssum[t] = s;
    __syncthreads();
    for (int off = 1; off < 1024; off <<= 1) {
        int v = ssum[t];
        int add = (t >= off) ? ssum[t-off] : 0;
        __syncthreads();
        ssum[t] = v + add;
        __syncthreads();
    }
    int prefix = (t == 0) ? 0 : ssum[t-1];
    #pragma unroll
    for (int i = 0; i < CH; ++i) rowptr[base+i] = prefix + loc[i];
    if (t == 0) rowptr[NNODES] = ssum[1023];
}

__global__ __launch_bounds__(256) void k_fill(const int* __restrict__ row, const int* __restrict__ col,
    const float* __restrict__ w, const float* __restrict__ dinv,
    const int* __restrict__ rowptr, int* __restrict__ fill,
    int* __restrict__ ecol, float* __restrict__ ea)
{
    int e = blockIdx.x*256 + threadIdx.x;
    if (e >= NE) return;
    int r = row[e], c = col[e];
    int pos = rowptr[r] + atomicAdd(&fill[r], 1);
    ecol[pos] = c;
    ea[pos] = w[e] * dinv[r] * dinv[c];
}

// ---------------- pack B into MFMA fragment order (bf16) ----------------
__global__ __launch_bounds__(256) void k_packB(const float* __restrict__ W, int Fin, int NF, int K,
    int mode, ushort* __restrict__ out)
{
    int t = blockIdx.x*256 + threadIdx.x;
    int lane = t & 63;
    int fid = t >> 6;
    if (fid >= (K/32)*NF) return;
    int kb = fid / NF, nb = fid % NF;
    int kbase = kb*32 + ((lane>>4)<<3);
    int n0 = nb*16 + (lane&15);
    #pragma unroll
    for (int j = 0; j < 8; ++j) {
        int kk = kbase + j;
        float v;
        if (mode == 0) {
            if (n0 < 64)       v = W[kk*64 + n0] - W[2*Fin*64 + kk*64 + n0];
            else if (n0 < 128) v = W[Fin*64 + kk*64 + (n0-64)];
            else               v = W[2*Fin*64 + kk*64 + (n0-128)];
        } else {
            v = W[(kk>>6)*64*256 + (kk&63)*256 + n0];
        }
        out[((long)fid*64 + lane)*8 + j] = f2b(v);
    }
}

// ---------------- MFMA GEMM ----------------
// AMODE 0: A bf16 node-major [r][64]  (r = n*4+b)
// AMODE 1: A fp32 batch-major [b*N+n][256] (converted in-register); C rows permuted to node-major
// AMODE 2: A = 3 bf16 parts node-major [r][64] concat along K (K=192)
// CMODE 0: C -> 3 bf16 arrays [crow][64]
// CMODE 1: C -> bf16 [r][256]
// CMODE 2: C -> fp32 batch-major [b*N+n][256]
template<int N_, int AMODE, int CMODE>
__global__ __launch_bounds__(256) void k_mgemm(
    const void* __restrict__ Aa, const void* __restrict__ Ab, const void* __restrict__ Ac,
    int K, const ushort* __restrict__ Bp,
    void* __restrict__ C0, void* __restrict__ C1, void* __restrict__ C2)
{
    const int NF = N_/16;
    int tid = threadIdx.x;
    int w = tid >> 6, l = tid & 63;
    int lr = l & 15, kg = l >> 4;
    long rb = (long)blockIdx.x * 128;
    f32x4 acc[2][NF];
    #pragma unroll
    for (int rf = 0; rf < 2; ++rf)
        #pragma unroll
        for (int nb = 0; nb < NF; ++nb) acc[rf][nb] = (f32x4){0.f,0.f,0.f,0.f};

    for (int kt = 0; kt < K; kt += 32) {
        s8v afr[2];
        #pragma unroll
        for (int rf = 0; rf < 2; ++rf) {
            long rg = rb + w*32 + rf*16 + lr;
            if (AMODE == 1) {
                const float* af = (const float*)Aa + rg*256 + kt + (kg<<3);
                float4 v0 = *(const float4*)af;
                float4 v1 = *(const float4*)(af + 4);
                s8v fr;
                fr[0]=(short)f2b(v0.x); fr[1]=(short)f2b(v0.y); fr[2]=(short)f2b(v0.z); fr[3]=(short)f2b(v0.w);
                fr[4]=(short)f2b(v1.x); fr[5]=(short)f2b(v1.y); fr[6]=(short)f2b(v1.z); fr[7]=(short)f2b(v1.w);
                afr[rf] = fr;
            } else if (AMODE == 0) {
                afr[rf] = *(const s8v*)((const ushort*)Aa + rg*64 + kt + (kg<<3));
            } else {
                int part = kt >> 6, kc = kt & 63;
                const ushort* ap = (part == 0) ? (const ushort*)Aa : ((part == 1) ? (const ushort*)Ab : (const ushort*)Ac);
                afr[rf] = *(const s8v*)(ap + rg*64 + kc + (kg<<3));
            }
        }
        const ushort* bb = Bp + ((long)(kt>>5)*NF)*512 + l*8;
        #pragma unroll
        for (int nb = 0; nb < NF; ++nb) {
            s8v bfr = *(const s8v*)(bb + nb*512);
            acc[0][nb] = __builtin_amdgcn_mfma_f32_16x16x32_bf16(afr[0], bfr, acc[0][nb], 0, 0, 0);
            acc[1][nb] = __builtin_amdgcn_mfma_f32_16x16x32_bf16(afr[1], bfr, acc[1][nb], 0, 0, 0);
        }
    }

    int b4 = 0, n0 = 0;
    if (AMODE == 1) { b4 = (int)(rb / NNODES); n0 = (int)(rb - (long)b4*NNODES); }
    #pragma unroll
    for (int rf = 0; rf < 2; ++rf) {
        #pragma unroll
        for (int nb = 0; nb < NF; ++nb) {
            #pragma unroll
            for (int i = 0; i < 4; ++i) {
                int lrw = w*32 + rf*16 + kg*4 + i;
                int cc = nb*16 + lr;
                float v = acc[rf][nb][i];
                if (CMODE == 0) {
                    long crow = (AMODE == 1) ? ((long)(n0 + lrw)*4 + b4) : (rb + lrw);
                    ushort* arr = (nb < 4) ? (ushort*)C0 : ((nb < 8) ? (ushort*)C1 : (ushort*)C2);
                    arr[crow*64 + (nb&3)*16 + lr] = f2b(v);
                } else if (CMODE == 1) {
                    ((ushort*)C0)[(rb + lrw)*256 + cc] = f2b(v);
                } else {
                    long r = rb + lrw;
                    int n = (int)(r >> 2), b = (int)(r & 3);
                    ((float*)C0)[((long)b*NNODES + n)*256 + cc] = v;
                }
            }
        }
    }
}

// ---------------- propagation (CSR gather, node-major bf16 [r=n*4+b][64]) ----------------
// dst = alpha*sum_e a[e]*src[col[e]] + beta*base   (512 B contiguous gather per edge)
__global__ __launch_bounds__(256) void k_prop(
    const int* __restrict__ rowptr, const int* __restrict__ ecol, const float* __restrict__ ea,
    const ushort* __restrict__ src, const ushort* __restrict__ basep, float beta,
    ushort* __restrict__ dst, float alpha)
{
    int g = blockIdx.x*8 + (threadIdx.x >> 5);
    int sub = threadIdx.x & 31;
    int e0 = rowptr[g], e1 = rowptr[g+1];
    float acc[8];
    #pragma unroll
    for (int j = 0; j < 8; ++j) acc[j] = 0.f;
    for (int e = e0; e < e1; ++e) {
        int c = ecol[e];
        float a = ea[e];
        s8v v = *(const s8v*)(src + (long)c*256 + sub*8);
        #pragma unroll
        for (int j = 0; j < 8; ++j) acc[j] += a * b2f((ushort)v[j]);
    }
    s8v o;
    if (basep) {
        s8v bv = *(const s8v*)(basep + (long)g*256 + sub*8);
        #pragma unroll
        for (int j = 0; j < 8; ++j) o[j] = (short)f2b(alpha*acc[j] + beta*b2f((ushort)bv[j]));
    } else {
        #pragma unroll
        for (int j = 0; j < 8; ++j) o[j] = (short)f2b(alpha*acc[j]);
    }
    *(s8v*)(dst + (long)g*256 + sub*8) = o;
}

// ---------------- instance-norm ----------------
// stats over bf16 node-major array [MTOT*64]  (elem e: b=(e>>6)&3, c=e&63)
__global__ __launch_bounds__(256) void k_statsA(const ushort* __restrict__ y,
    float* __restrict__ sum, float* __restrict__ sumsq)
{
    int t = threadIdx.x;
    float s[8], q[8];
    #pragma unroll
    for (int j = 0; j < 8; ++j) { s[j] = 0.f; q[j] = 0.f; }
    for (int i = 0; i < 12; ++i) {
        long e = ((long)(i*512 + blockIdx.x))*2048 + t*8;
        s8v v = *(const s8v*)(y + e);
        #pragma unroll
        for (int j = 0; j < 8; ++j) { float f = b2f((ushort)v[j]); s[j] += f; q[j] += f*f; }
    }
    __shared__ float ls[256][8], lq[256][8];
    #pragma unroll
    for (int j = 0; j < 8; ++j) { ls[t][j] = s[j]; lq[t][j] = q[j]; }
    __syncthreads();
    #pragma unroll
    for (int off = 128; off >= 32; off >>= 1) {
        if (t < off) {
            #pragma unroll
            for (int j = 0; j < 8; ++j) { ls[t][j] += ls[t+off][j]; lq[t][j] += lq[t+off][j]; }
        }
        __syncthreads();
    }
    if (t < 32) {
        int b = (t>>3)&3, c0 = (t&7)*8;
        #pragma unroll
        for (int j = 0; j < 8; ++j) {
            atomicAdd(&sum[b*256 + c0 + j], ls[t][j]);
            atomicAdd(&sumsq[b*256 + c0 + j], lq[t][j]);
        }
    }
}

// stats over bf16 node-major Y [MTOT*256]  (elem e: b=(e>>8)&3, c=e&255)
__global__ __launch_bounds__(256) void k_statsY(const ushort* __restrict__ y,
    float* __restrict__ sum, float* __restrict__ sumsq)
{
    int t = threadIdx.x;
    float s[8], q[8];
    #pragma unroll
    for (int j = 0; j < 8; ++j) { s[j] = 0.f; q[j] = 0.f; }
    for (int i = 0; i < 48; ++i) {
        long e = ((long)(i*512 + blockIdx.x))*2048 + t*8;
        s8v v = *(const s8v*)(y + e);
        #pragma unroll
        for (int j = 0; j < 8; ++j) { float f = b2f((ushort)v[j]); s[j] += f; q[j] += f*f; }
    }
    __shared__ float ls[256][8], lq[256][8];
    #pragma unroll
    for (int j = 0; j < 8; ++j) { ls[t][j] = s[j]; lq[t][j] = q[j]; }
    __syncthreads();
    if (t < 128) {
        #pragma unroll
        for (int j = 0; j < 8; ++j) { ls[t][j] += ls[t+128][j]; lq[t][j] += lq[t+128][j]; }
    }
    __syncthreads();
    if (t < 128) {
        int b = (t>>5)&3, c0 = (t&31)*8;
        #pragma unroll
        for (int j = 0; j < 8; ++j) {
            atomicAdd(&sum[b*256 + c0 + j], ls[t][j]);
            atomicAdd(&sumsq[b*256 + c0 + j], lq[t][j]);
        }
    }
}

__global__ __launch_bounds__(256) void k_finalize(const float* __restrict__ sum,
    const float* __restrict__ sumsq, float* __restrict__ mean, float* __restrict__ rs, int C_)
{
    int i = blockIdx.x*256 + threadIdx.x;
    if (i >= NB*256) return;
    int c = i % 256;
    if (c >= C_) return;
    float m = sum[i] / (float)NNODES;
    float v = sumsq[i] / (float)NNODES - m*m;
    mean[i] = m;
    rs[i] = rsqrtf(v + EPS);
}

// X = relu((y-mean)*rs), node-major [MTOT*64] bf16
__global__ __launch_bounds__(256) void k_normrelu(const ushort* __restrict__ y,
    const float* __restrict__ mean, const float* __restrict__ rs, ushort* __restrict__ X)
{
    int t = threadIdx.x;
    long e = (long)blockIdx.x*2048 + t*8;
    int b = (t>>3)&3, c0 = (t&7)*8;
    s8v v = *(const s8v*)(y + e);
    float4 m0 = *(const float4*)(mean + b*256 + c0);
    float4 m1 = *(const float4*)(mean + b*256 + c0 + 4);
    float4 r0 = *(const float4*)(rs + b*256 + c0);
    float4 r1 = *(const float4*)(rs + b*256 + c0 + 4);
    float mm[8] = {m0.x,m0.y,m0.z,m0.w,m1.x,m1.y,m1.z,m1.w};
    float rr[8] = {r0.x,r0.y,r0.z,r0.w,r1.x,r1.y,r1.z,r1.w};
    s8v o;
    #pragma unroll
    for (int j = 0; j < 8; ++j) o[j] = (short)f2b(fmaxf((b2f((ushort)v[j]) - mm[j])*rr[j], 0.f));
    *(s8v*)(X + e) = o;
}

// out[(b*N+n)*256+c] = relu((Ybf[(n*4+b)*256+c]-mean)*rs) + x  (main path)
__global__ __launch_bounds__(256) void k_final(const ushort* __restrict__ Ybf,
    const float* __restrict__ x, const float* __restrict__ mean, const float* __restrict__ rs,
    float* __restrict__ out)
{
    int t = threadIdx.x;
    long orow = (long)blockIdx.x*8 + (t>>5);
    int c0 = (t&31)*8;
    int b = (int)(orow / NNODES);
    int n = (int)(orow - (long)b*NNODES);
    s8v v = *(const s8v*)(Ybf + ((long)n*4 + b)*256 + c0);
    float4 m0 = *(const float4*)(mean + b*256 + c0);
    float4 m1 = *(const float4*)(mean + b*256 + c0 + 4);
    float4 r0 = *(const float4*)(rs + b*256 + c0);
    float4 r1 = *(const float4*)(rs + b*256 + c0 + 4);
    float mm[8] = {m0.x,m0.y,m0.z,m0.w,m1.x,m1.y,m1.z,m1.w};
    float rr[8] = {r0.x,r0.y,r0.z,r0.w,r1.x,r1.y,r1.z,r1.w};
    const float* xp = x + orow*256 + c0;
    float* op = out + orow*256 + c0;
    #pragma unroll
    for (int j = 0; j < 8; ++j)
        op[j] = fmaxf((b2f((ushort)v[j]) - mm[j])*rr[j], 0.f) + xp[j];
}

// ---- fallback path (fp32 Y in d_out, batch-major) ----
__global__ __launch_bounds__(256) void k_stats256f(const float* __restrict__ y,
    float* __restrict__ sum, float* __restrict__ sumsq)
{
    int b = blockIdx.y;
    int c = threadIdx.x;
    long r0 = (long)blockIdx.x*256;
    float s = 0.f, ss = 0.f;
    for (int r = 0; r < 256; ++r) {
        float v = y[((long)b*NNODES + r0 + r)*256 + c];
        s += v; ss += v*v;
    }
    atomicAdd(&sum[b*256 + c], s);
    atomicAdd(&sumsq[b*256 + c], ss);
}

__global__ __launch_bounds__(256) void k_finalf(float* __restrict__ Y,
    const float* __restrict__ x, const float* __restrict__ mean, const float* __restrict__ rs)
{
    long idx = (long)blockIdx.x*256 + threadIdx.x;
    long bn = idx >> 6;
    int q = (int)(idx & 63);
    int b = (int)(bn / NNODES);
    float4 v = *(const float4*)(Y + bn*256 + q*4);
    float4 m = *(const float4*)(mean + b*256 + q*4);
    float4 r_ = *(const float4*)(rs + b*256 + q*4);
    float4 xv = *(const float4*)(x + bn*256 + q*4);
    float4 o;
    o.x = fmaxf((v.x-m.x)*r_.x, 0.f) + xv.x;
    o.y = fmaxf((v.y-m.y)*r_.y, 0.f) + xv.y;
    o.z = fmaxf((v.z-m.z)*r_.z, 0.f) + xv.z;
    o.w = fmaxf((v.w-m.w)*r_.w, 0.f) + xv.w;
    *(float4*)(Y + bn*256 + q*4) = o;
}

extern "C" void kernel_launch(void* const* d_in, const int* in_sizes, int n_in,
                              void* d_out, int out_size, void* d_ws, size_t ws_size,
                              hipStream_t stream)
{
    const float* x  = (const float*)d_in[0];
    const int*   ei = (const int*)d_in[1];
    const float* ew = (const float*)d_in[2];
    const float* W1 = (const float*)d_in[3];
    const float* W2 = (const float*)d_in[5];
    const float* W3 = (const float*)d_in[7];
    const int* row = ei;
    const int* col = ei + NE;

    char* p = (char*)d_ws;
    size_t used = 0;
    auto alloc = [&](size_t bytes) -> void* {
        void* r = p + used;
        used += (bytes + 1023) & ~(size_t)1023;
        return r;
    };
    float* deg   = (float*)alloc((size_t)3*NNODES*4);     // deg | cnt | fill
    int*   cnt   = (int*)(deg + NNODES);
    int*   fillc = (int*)(deg + 2*NNODES);
    float* stats = (float*)alloc((size_t)3*2*1024*4);     // 3 layers x (sum|sumsq)[1024]
    float* dinv  = (float*)alloc((size_t)NNODES*4);
    int*   rowptr= (int*)alloc((size_t)(NNODES+1)*4);
    int*   ecol  = (int*)alloc((size_t)NE*4);
    float* ea    = (float*)alloc((size_t)NE*4);
    float* mrs   = (float*)alloc((size_t)3*2*1024*4);     // 3 layers x (mean|rs)[1024]
    ushort* Bp1  = (ushort*)alloc((size_t)256*192*2);
    ushort* Bp2  = (ushort*)alloc((size_t)64*192*2);
    ushort* Bp3  = (ushort*)alloc((size_t)192*256*2);
    ushort* Za   = (ushort*)alloc((size_t)MTOT*64*2);
    ushort* Zb   = (ushort*)alloc((size_t)MTOT*64*2);
    ushort* Zc   = (ushort*)alloc((size_t)MTOT*64*2);
    ushort* Zd   = (ushort*)alloc((size_t)MTOT*64*2);
    size_t need_fb = used;
    ushort* Ybf  = (ushort*)alloc((size_t)MTOT*256*2);
    size_t need_main = used;
    if (ws_size < need_fb) return;
    bool mainPath = ws_size >= need_main;

    float* sum1 = stats;           float* sq1 = stats + 1024;
    float* sum2 = stats + 2048;    float* sq2 = stats + 3072;
    float* sum3 = stats + 4096;    float* sq3 = stats + 5120;
    float* mean1 = mrs;            float* rs1 = mrs + 1024;
    float* mean2 = mrs + 2048;     float* rs2 = mrs + 3072;
    float* mean3 = mrs + 4096;     float* rs3 = mrs + 5120;

    // ---- setup (deg/cnt/fill + all stats zeroed in one memset; contiguous) ----
    hipMemsetAsync(deg, 0, (size_t)3*NNODES*4 + (size_t)3*2*1024*4, stream);
    k_deg_cnt<<<NE/256, 256, 0, stream>>>(row, ew, deg, cnt);
    k_dinv<<<NNODES/256, 256, 0, stream>>>(deg, dinv);
    k_scan<<<1, 1024, 0, stream>>>(cnt, rowptr);
    k_fill<<<NE/256, 256, 0, stream>>>(row, col, ew, dinv, rowptr, fillc, ecol, ea);
    k_packB<<<24, 256, 0, stream>>>(W1, 256, 12, 256, 0, Bp1);
    k_packB<<<6, 256, 0, stream>>>(W2, 64, 12, 64, 0, Bp2);
    k_packB<<<24, 256, 0, stream>>>(W3, 64, 16, 192, 1, Bp3);

    // ---- layer 1: 256 -> 64 (outputs node-major: Za=y0, Zb=u1, Zc=u2) ----
    k_mgemm<192,1,0><<<MTOT/128, 256, 0, stream>>>(x, nullptr, nullptr, 256, Bp1, Za, Zb, Zc);
    k_prop<<<NNODES/8, 256, 0, stream>>>(rowptr, ecol, ea, Zc, Zb, 1.f, Zb, -2.f);  // z = u1 - 2S(u2)
    k_prop<<<NNODES/8, 256, 0, stream>>>(rowptr, ecol, ea, Zb, Za, 1.f, Za, -1.f);  // y = y0 - S(z)
    k_statsA<<<512, 256, 0, stream>>>(Za, sum1, sq1);
    k_finalize<<<4, 256, 0, stream>>>(sum1, sq1, mean1, rs1, 64);
    k_normrelu<<<MTOT*64/2048, 256, 0, stream>>>(Za, mean1, rs1, Zc);   // X2 = Zc

    // ---- layer 2: 64 -> 64 ----
    k_mgemm<192,0,0><<<MTOT/128, 256, 0, stream>>>(Zc, nullptr, nullptr, 64, Bp2, Za, Zb, Zd);
    k_prop<<<NNODES/8, 256, 0, stream>>>(rowptr, ecol, ea, Zd, Zb, 1.f, Zb, -2.f);
    k_prop<<<NNODES/8, 256, 0, stream>>>(rowptr, ecol, ea, Zb, Za, 1.f, Za, -1.f);
    k_statsA<<<512, 256, 0, stream>>>(Za, sum2, sq2);
    k_finalize<<<4, 256, 0, stream>>>(sum2, sq2, mean2, rs2, 64);
    k_normrelu<<<MTOT*64/2048, 256, 0, stream>>>(Za, mean2, rs2, Zc);   // X3 = Zc

    // ---- layer 3: 64 -> 256 (propagate in 64-dim input space) ----
    k_prop<<<NNODES/8, 256, 0, stream>>>(rowptr, ecol, ea, Zc, (const ushort*)nullptr, 0.f, Za, -1.f); // T1
    k_prop<<<NNODES/8, 256, 0, stream>>>(rowptr, ecol, ea, Za, Zc, -1.f, Zb, -2.f);                    // T2
    if (mainPath) {
        k_mgemm<256,2,1><<<MTOT/128, 256, 0, stream>>>(Zc, Za, Zb, 192, Bp3, Ybf, nullptr, nullptr);
        k_statsY<<<512, 256, 0, stream>>>(Ybf, sum3, sq3);
        k_finalize<<<4, 256, 0, stream>>>(sum3, sq3, mean3, rs3, 256);
        k_final<<<MTOT*256/2048, 256, 0, stream>>>(Ybf, x, mean3, rs3, (float*)d_out);
    } else {
        float* Y = (float*)d_out;
        k_mgemm<256,2,2><<<MTOT/128, 256, 0, stream>>>(Zc, Za, Zb, 192, Bp3, Y, nullptr, nullptr);
        k_stats256f<<<dim3(NNODES/256, NB), 256, 0, stream>>>(Y, sum3, sq3);
        k_finalize<<<4, 256, 0, stream>>>(sum3, sq3, mean3, rs3, 256);
        k_finalf<<<MTOT*64/256, 256, 0, stream>>>(Y, x, mean3, rs3);
    }
}

// Round 4
// 716.956 us; speedup vs baseline: 1.3265x; 1.3265x over previous
//
#include <hip/hip_runtime.h>

#define NNODES 49152
#define NB 4
#define NE 393216
#define MTOT (NB*NNODES)
#define EPS 1e-5f

typedef __attribute__((ext_vector_type(8))) short s8v;   // 8 x bf16 (raw)
typedef __attribute__((ext_vector_type(4))) float f32x4;

__device__ inline float b2f(ushort u){ union{uint i; float f;} v; v.i = ((uint)u)<<16; return v.f; }
__device__ inline ushort f2b(float f){ union{float f; uint i;} v; v.f=f; uint r = v.i + 0x7fff + ((v.i>>16)&1); return (ushort)(r>>16); }

// ---------------- setup kernels ----------------
__global__ __launch_bounds__(256) void k_deg_cnt(const int* __restrict__ row,
    const float* __restrict__ w, float* __restrict__ deg, int* __restrict__ cnt)
{
    int e = blockIdx.x*256 + threadIdx.x;
    if (e >= NE) return;
    int r = row[e];
    atomicAdd(&deg[r], w[e]);
    atomicAdd(&cnt[r], 1);
}

__global__ __launch_bounds__(256) void k_dinv(const float* __restrict__ deg, float* __restrict__ dinv)
{
    int i = blockIdx.x*256 + threadIdx.x;
    if (i >= NNODES) return;
    float d = deg[i];
    dinv[i] = (d > 0.0f) ? rsqrtf(fmaxf(d, EPS)) : 0.0f;
}

__global__ __launch_bounds__(1024) void k_scan(const int* __restrict__ cnt, int* __restrict__ rowptr)
{
    __shared__ int ssum[1024];
    const int CH = NNODES/1024; // 48
    int t = threadIdx.x;
    int base = t*CH;
    int loc[CH];
    int s = 0;
    #pragma unroll
    for (int i = 0; i < CH; ++i) { loc[i] = s; s += cnt[base+i]; }
    ssum[t] = s;
    __syncthreads();
    for (int off = 1; off < 1024; off <<= 1) {
        int v = ssum[t];
        int add = (t >= off) ? ssum[t-off] : 0;
        __syncthreads();
        ssum[t] = v + add;
        __syncthreads();
    }
    int prefix = (t == 0) ? 0 : ssum[t-1];
    #pragma unroll
    for (int i = 0; i < CH; ++i) rowptr[base+i] = prefix + loc[i];
    if (t == 0) rowptr[NNODES] = ssum[1023];
}

__global__ __launch_bounds__(256) void k_fill(const int* __restrict__ row, const int* __restrict__ col,
    const float* __restrict__ w, const float* __restrict__ dinv,
    const int* __restrict__ rowptr, int* __restrict__ fill,
    int* __restrict__ ecol, float* __restrict__ ea)
{
    int e = blockIdx.x*256 + threadIdx.x;
    if (e >= NE) return;
    int r = row[e], c = col[e];
    int pos = rowptr[r] + atomicAdd(&fill[r], 1);
    ecol[pos] = c;
    ea[pos] = w[e] * dinv[r] * dinv[c];
}

// ---------------- pack B into MFMA fragment order (bf16) ----------------
__global__ __launch_bounds__(256) void k_packB(const float* __restrict__ W, int Fin, int NF, int K,
    int mode, ushort* __restrict__ out)
{
    int t = blockIdx.x*256 + threadIdx.x;
    int lane = t & 63;
    int fid = t >> 6;
    if (fid >= (K/32)*NF) return;
    int kb = fid / NF, nb = fid % NF;
    int kbase = kb*32 + ((lane>>4)<<3);
    int n0 = nb*16 + (lane&15);
    #pragma unroll
    for (int j = 0; j < 8; ++j) {
        int kk = kbase + j;
        float v;
        if (mode == 0) {
            if (n0 < 64)       v = W[kk*64 + n0] - W[2*Fin*64 + kk*64 + n0];
            else if (n0 < 128) v = W[Fin*64 + kk*64 + (n0-64)];
            else               v = W[2*Fin*64 + kk*64 + (n0-128)];
        } else {
            v = W[(kk>>6)*64*256 + (kk&63)*256 + n0];
        }
        out[((long)fid*64 + lane)*8 + j] = f2b(v);
    }
}

// ---------------- GEMM1: fp32 x[b*N+n][256] @ Bp1 -> 3 bf16 node-major [n*4+b][64] ----------------
// grid over nodes (32/block); wave w handles batch w -> each block emits complete node-major lines.
__global__ __launch_bounds__(256) void k_gemm1(const float* __restrict__ A,
    const ushort* __restrict__ Bp, ushort* __restrict__ C0, ushort* __restrict__ C1, ushort* __restrict__ C2)
{
    int tid = threadIdx.x;
    int w = tid >> 6, l = tid & 63;
    int lr = l & 15, kg = l >> 4;
    int n0 = blockIdx.x * 32;
    f32x4 acc[2][12];
    #pragma unroll
    for (int rf = 0; rf < 2; ++rf)
        #pragma unroll
        for (int nb = 0; nb < 12; ++nb) acc[rf][nb] = (f32x4){0.f,0.f,0.f,0.f};

    for (int kt = 0; kt < 256; kt += 32) {
        s8v afr[2];
        #pragma unroll
        for (int rf = 0; rf < 2; ++rf) {
            long rowg = (long)w*NNODES + n0 + rf*16 + lr;
            const float* af = A + rowg*256 + kt + (kg<<3);
            float4 v0 = *(const float4*)af;
            float4 v1 = *(const float4*)(af + 4);
            s8v fr;
            fr[0]=(short)f2b(v0.x); fr[1]=(short)f2b(v0.y); fr[2]=(short)f2b(v0.z); fr[3]=(short)f2b(v0.w);
            fr[4]=(short)f2b(v1.x); fr[5]=(short)f2b(v1.y); fr[6]=(short)f2b(v1.z); fr[7]=(short)f2b(v1.w);
            afr[rf] = fr;
        }
        const ushort* bb = Bp + ((long)(kt>>5)*12)*512 + l*8;
        #pragma unroll
        for (int nb = 0; nb < 12; ++nb) {
            s8v bfr = *(const s8v*)(bb + nb*512);
            acc[0][nb] = __builtin_amdgcn_mfma_f32_16x16x32_bf16(afr[0], bfr, acc[0][nb], 0, 0, 0);
            acc[1][nb] = __builtin_amdgcn_mfma_f32_16x16x32_bf16(afr[1], bfr, acc[1][nb], 0, 0, 0);
        }
    }
    #pragma unroll
    for (int rf = 0; rf < 2; ++rf) {
        #pragma unroll
        for (int nb = 0; nb < 12; ++nb) {
            ushort* arr = (nb < 4) ? C0 : ((nb < 8) ? C1 : C2);
            #pragma unroll
            for (int i = 0; i < 4; ++i) {
                long crow = ((long)(n0 + rf*16 + kg*4 + i))*4 + w;   // node-major [n][b]
                arr[crow*64 + (nb&3)*16 + lr] = f2b(acc[rf][nb][i]);
            }
        }
    }
}

// ---------------- GEMM2: bf16 node-major X[r][64] @ Bp2 -> 3 bf16 node-major [r][64] ----------------
__global__ __launch_bounds__(256) void k_gemm2(const ushort* __restrict__ A,
    const ushort* __restrict__ Bp, ushort* __restrict__ C0, ushort* __restrict__ C1, ushort* __restrict__ C2)
{
    int tid = threadIdx.x;
    int w = tid >> 6, l = tid & 63;
    int lr = l & 15, kg = l >> 4;
    long rb = (long)blockIdx.x * 128;
    f32x4 acc[2][12];
    #pragma unroll
    for (int rf = 0; rf < 2; ++rf)
        #pragma unroll
        for (int nb = 0; nb < 12; ++nb) acc[rf][nb] = (f32x4){0.f,0.f,0.f,0.f};

    #pragma unroll
    for (int kt = 0; kt < 64; kt += 32) {
        s8v afr[2];
        #pragma unroll
        for (int rf = 0; rf < 2; ++rf) {
            long rg = rb + w*32 + rf*16 + lr;
            afr[rf] = *(const s8v*)(A + rg*64 + kt + (kg<<3));
        }
        const ushort* bb = Bp + ((long)(kt>>5)*12)*512 + l*8;
        #pragma unroll
        for (int nb = 0; nb < 12; ++nb) {
            s8v bfr = *(const s8v*)(bb + nb*512);
            acc[0][nb] = __builtin_amdgcn_mfma_f32_16x16x32_bf16(afr[0], bfr, acc[0][nb], 0, 0, 0);
            acc[1][nb] = __builtin_amdgcn_mfma_f32_16x16x32_bf16(afr[1], bfr, acc[1][nb], 0, 0, 0);
        }
    }
    #pragma unroll
    for (int rf = 0; rf < 2; ++rf) {
        #pragma unroll
        for (int nb = 0; nb < 12; ++nb) {
            ushort* arr = (nb < 4) ? C0 : ((nb < 8) ? C1 : C2);
            #pragma unroll
            for (int i = 0; i < 4; ++i) {
                long crow = rb + w*32 + rf*16 + kg*4 + i;
                arr[crow*64 + (nb&3)*16 + lr] = f2b(acc[rf][nb][i]);
            }
        }
    }
}

// ---------------- GEMM3: 3 bf16 node-major parts (K=192) -> bf16 Ybf[r][256] + fused stats ----------------
// row%4 == batch (rb,w*32,rf*16,kg*4 all ≡0 mod 4) -> acc index i IS the batch.
__global__ __launch_bounds__(256) void k_gemm3(const ushort* __restrict__ A0,
    const ushort* __restrict__ A1, const ushort* __restrict__ A2,
    const ushort* __restrict__ Bp, ushort* __restrict__ C, float* __restrict__ Pst)
{
    int tid = threadIdx.x;
    int w = tid >> 6, l = tid & 63;
    int lr = l & 15, kg = l >> 4;
    long rb = (long)blockIdx.x * 128;
    f32x4 acc[2][16];
    #pragma unroll
    for (int rf = 0; rf < 2; ++rf)
        #pragma unroll
        for (int nb = 0; nb < 16; ++nb) acc[rf][nb] = (f32x4){0.f,0.f,0.f,0.f};

    for (int kt = 0; kt < 192; kt += 32) {
        int part = kt >> 6, kc = kt & 63;
        const ushort* Ap = (part == 0) ? A0 : ((part == 1) ? A1 : A2);
        s8v afr[2];
        #pragma unroll
        for (int rf = 0; rf < 2; ++rf) {
            long rg = rb + w*32 + rf*16 + lr;
            afr[rf] = *(const s8v*)(Ap + rg*64 + kc + (kg<<3));
        }
        const ushort* bb = Bp + ((long)(kt>>5)*16)*512 + l*8;
        #pragma unroll
        for (int nb = 0; nb < 16; ++nb) {
            s8v bfr = *(const s8v*)(bb + nb*512);
            acc[0][nb] = __builtin_amdgcn_mfma_f32_16x16x32_bf16(afr[0], bfr, acc[0][nb], 0, 0, 0);
            acc[1][nb] = __builtin_amdgcn_mfma_f32_16x16x32_bf16(afr[1], bfr, acc[1][nb], 0, 0, 0);
        }
    }
    // C write
    #pragma unroll
    for (int rf = 0; rf < 2; ++rf) {
        #pragma unroll
        for (int nb = 0; nb < 16; ++nb) {
            #pragma unroll
            for (int i = 0; i < 4; ++i) {
                long crow = rb + w*32 + rf*16 + kg*4 + i;
                C[crow*256 + nb*16 + lr] = f2b(acc[rf][nb][i]);
            }
        }
    }
    // fused per-block channel stats (no atomics)
    __shared__ float Ls[4][4][256];
    __shared__ float Lq[4][4][256];
    #pragma unroll
    for (int nb = 0; nb < 16; ++nb) {
        #pragma unroll
        for (int i = 0; i < 4; ++i) {
            float x0 = acc[0][nb][i], x1 = acc[1][nb][i];
            float s = x0 + x1;
            float q = x0*x0 + x1*x1;
            s += __shfl_xor(s, 16); s += __shfl_xor(s, 32);
            q += __shfl_xor(q, 16); q += __shfl_xor(q, 32);
            if (kg == 0) { Ls[w][i][nb*16 + lr] = s; Lq[w][i][nb*16 + lr] = q; }
        }
    }
    __syncthreads();
    int t = tid;  // col
    #pragma unroll
    for (int b = 0; b < 4; ++b) {
        float S = Ls[0][b][t] + Ls[1][b][t] + Ls[2][b][t] + Ls[3][b][t];
        float Q = Lq[0][b][t] + Lq[1][b][t] + Lq[2][b][t] + Lq[3][b][t];
        Pst[(long)blockIdx.x*2048 + b*256 + t] = S;
        Pst[(long)blockIdx.x*2048 + 1024 + b*256 + t] = Q;
    }
}

// ---------------- propagation (CSR gather, node-major bf16 [n][b*64+c], 4-deep pipelined) ----------------
// dst = alpha*sum_e a[e]*src[col[e]] + beta*base ; optional per-block stats partials (atomic-free)
__global__ __launch_bounds__(256) void k_prop(
    const int* __restrict__ rowptr, const int* __restrict__ ecol, const float* __restrict__ ea,
    const ushort* __restrict__ src, const ushort* __restrict__ basep, float beta,
    ushort* __restrict__ dst, float alpha, float* __restrict__ Pst)
{
    int g = blockIdx.x*8 + (threadIdx.x >> 5);
    int sub = threadIdx.x & 31;
    int e0 = rowptr[g], e1 = rowptr[g+1];
    float acc[8];
    #pragma unroll
    for (int j = 0; j < 8; ++j) acc[j] = 0.f;
    int e = e0;
    for (; e + 4 <= e1; e += 4) {
        int c0 = ecol[e], c1 = ecol[e+1], c2 = ecol[e+2], c3 = ecol[e+3];
        float a0 = ea[e], a1 = ea[e+1], a2 = ea[e+2], a3 = ea[e+3];
        s8v v0 = *(const s8v*)(src + (long)c0*256 + sub*8);
        s8v v1 = *(const s8v*)(src + (long)c1*256 + sub*8);
        s8v v2 = *(const s8v*)(src + (long)c2*256 + sub*8);
        s8v v3 = *(const s8v*)(src + (long)c3*256 + sub*8);
        #pragma unroll
        for (int j = 0; j < 8; ++j)
            acc[j] += a0*b2f((ushort)v0[j]) + a1*b2f((ushort)v1[j])
                    + a2*b2f((ushort)v2[j]) + a3*b2f((ushort)v3[j]);
    }
    for (; e < e1; ++e) {
        int c = ecol[e]; float a = ea[e];
        s8v v = *(const s8v*)(src + (long)c*256 + sub*8);
        #pragma unroll
        for (int j = 0; j < 8; ++j) acc[j] += a*b2f((ushort)v[j]);
    }
    float o[8];
    if (basep) {
        s8v bv = *(const s8v*)(basep + (long)g*256 + sub*8);
        #pragma unroll
        for (int j = 0; j < 8; ++j) o[j] = alpha*acc[j] + beta*b2f((ushort)bv[j]);
    } else {
        #pragma unroll
        for (int j = 0; j < 8; ++j) o[j] = alpha*acc[j];
    }
    s8v ov;
    #pragma unroll
    for (int j = 0; j < 8; ++j) ov[j] = (short)f2b(o[j]);
    *(s8v*)(dst + (long)g*256 + sub*8) = ov;

    if (Pst) {
        __shared__ float Ls[8][256];
        __shared__ float Lq[8][256];
        int grp = threadIdx.x >> 5;
        #pragma unroll
        for (int j = 0; j < 8; ++j) {
            Ls[grp][sub*8 + j] = o[j];
            Lq[grp][sub*8 + j] = o[j]*o[j];
        }
        __syncthreads();
        int t = threadIdx.x;   // t = b*64 + c
        float s = 0.f, q = 0.f;
        #pragma unroll
        for (int k = 0; k < 8; ++k) { s += Ls[k][t]; q += Lq[k][t]; }
        Pst[(long)blockIdx.x*512 + t] = s;
        Pst[(long)blockIdx.x*512 + 256 + t] = q;
    }
}

// ---------------- tree reduction (atomic-free) ----------------
// out[o][S] = sum_{k<nin} in[o*nin + k][S]
__global__ __launch_bounds__(256) void k_redgen(const float* __restrict__ in, float* __restrict__ out,
    int S, int nin)
{
    int j = blockIdx.x*256 + threadIdx.x;
    int o = blockIdx.y;
    long base = (long)o*nin*S + j;
    float s = 0.f;
    for (int k = 0; k < nin; ++k) s += in[base + (long)k*S];
    out[(long)o*S + j] = s;
}

// final: in[nin][S], S=2*half (sums | sqs) -> mean/rs;  j = b*Cw + c
__global__ __launch_bounds__(256) void k_redfin(const float* __restrict__ in, int S, int nin, int Cw,
    float* __restrict__ mean, float* __restrict__ rs)
{
    int half = S >> 1;
    int j = blockIdx.x*256 + threadIdx.x;
    if (j >= half) return;
    float s = 0.f, q = 0.f;
    for (int k = 0; k < nin; ++k) {
        s += in[(long)k*S + j];
        q += in[(long)k*S + half + j];
    }
    float m = s / (float)NNODES;
    float v = q / (float)NNODES - m*m;
    int b = j / Cw, c = j - b*Cw;
    mean[b*256 + c] = m;
    rs[b*256 + c] = rsqrtf(v + EPS);
}

// ---------------- norm-relu (node-major [MTOT*64] bf16) ----------------
__global__ __launch_bounds__(256) void k_normrelu(const ushort* __restrict__ y,
    const float* __restrict__ mean, const float* __restrict__ rs, ushort* __restrict__ X)
{
    int t = threadIdx.x;
    long e = (long)blockIdx.x*2048 + t*8;
    int b = (t>>3)&3, c0 = (t&7)*8;
    s8v v = *(const s8v*)(y + e);
    float4 m0 = *(const float4*)(mean + b*256 + c0);
    float4 m1 = *(const float4*)(mean + b*256 + c0 + 4);
    float4 r0 = *(const float4*)(rs + b*256 + c0);
    float4 r1 = *(const float4*)(rs + b*256 + c0 + 4);
    float mm[8] = {m0.x,m0.y,m0.z,m0.w,m1.x,m1.y,m1.z,m1.w};
    float rr[8] = {r0.x,r0.y,r0.z,r0.w,r1.x,r1.y,r1.z,r1.w};
    s8v o;
    #pragma unroll
    for (int j = 0; j < 8; ++j) o[j] = (short)f2b(fmaxf((b2f((ushort)v[j]) - mm[j])*rr[j], 0.f));
    *(s8v*)(X + e) = o;
}

// ---------------- final: out[(b*N+n)*256+c] = relu((Ybf[(n*4+b)*256+c]-mean)*rs) + x ----------------
__global__ __launch_bounds__(256) void k_final(const ushort* __restrict__ Ybf,
    const float* __restrict__ x, const float* __restrict__ mean, const float* __restrict__ rs,
    float* __restrict__ out)
{
    int t = threadIdx.x;
    long orow = (long)blockIdx.x*8 + (t>>5);
    int c0 = (t&31)*8;
    int b = (int)(orow / NNODES);
    int n = (int)(orow - (long)b*NNODES);
    s8v v = *(const s8v*)(Ybf + ((long)n*4 + b)*256 + c0);
    float4 m0 = *(const float4*)(mean + b*256 + c0);
    float4 m1 = *(const float4*)(mean + b*256 + c0 + 4);
    float4 r0 = *(const float4*)(rs + b*256 + c0);
    float4 r1 = *(const float4*)(rs + b*256 + c0 + 4);
    float mm[8] = {m0.x,m0.y,m0.z,m0.w,m1.x,m1.y,m1.z,m1.w};
    float rr[8] = {r0.x,r0.y,r0.z,r0.w,r1.x,r1.y,r1.z,r1.w};
    const float* xp = x + orow*256 + c0;
    float* op = out + orow*256 + c0;
    #pragma unroll
    for (int j = 0; j < 8; ++j)
        op[j] = fmaxf((b2f((ushort)v[j]) - mm[j])*rr[j], 0.f) + xp[j];
}

extern "C" void kernel_launch(void* const* d_in, const int* in_sizes, int n_in,
                              void* d_out, int out_size, void* d_ws, size_t ws_size,
                              hipStream_t stream)
{
    const float* x  = (const float*)d_in[0];
    const int*   ei = (const int*)d_in[1];
    const float* ew = (const float*)d_in[2];
    const float* W1 = (const float*)d_in[3];
    const float* W2 = (const float*)d_in[5];
    const float* W3 = (const float*)d_in[7];
    const int* row = ei;
    const int* col = ei + NE;

    char* p = (char*)d_ws;
    size_t used = 0;
    auto alloc = [&](size_t bytes) -> void* {
        void* r = p + used;
        used += (bytes + 1023) & ~(size_t)1023;
        return r;
    };
    float* deg   = (float*)alloc((size_t)3*NNODES*4);     // deg | cnt | fill (zeroed)
    int*   cnt   = (int*)(deg + NNODES);
    int*   fillc = (int*)(deg + 2*NNODES);
    float* dinv  = (float*)alloc((size_t)NNODES*4);
    int*   rowptr= (int*)alloc((size_t)(NNODES+1)*4);
    int*   ecol  = (int*)alloc((size_t)NE*4);
    float* ea    = (float*)alloc((size_t)NE*4);
    float* mrs   = (float*)alloc((size_t)3*2*1024*4);     // per layer: mean[1024] | rs[1024]
    ushort* Bp1  = (ushort*)alloc((size_t)256*192*2);
    ushort* Bp2  = (ushort*)alloc((size_t)64*192*2);
    ushort* Bp3  = (ushort*)alloc((size_t)192*256*2);
    ushort* Za   = (ushort*)alloc((size_t)MTOT*64*2);
    ushort* Zb   = (ushort*)alloc((size_t)MTOT*64*2);
    ushort* Zc   = (ushort*)alloc((size_t)MTOT*64*2);
    ushort* Zd   = (ushort*)alloc((size_t)MTOT*64*2);
    float* Pbig  = (float*)alloc((size_t)6144*512*4);     // 12.6 MB (also holds 1536x2048)
    float* PPa   = (float*)alloc((size_t)256*2048*4);     // 2 MB
    float* PPb   = (float*)alloc((size_t)16*2048*4);      // 128 KB
    ushort* Ybf  = (ushort*)alloc((size_t)MTOT*256*2);    // 100 MB
    if (ws_size < used) return;

    float* mean1 = mrs;          float* rs1 = mrs + 1024;
    float* mean2 = mrs + 2048;   float* rs2 = mrs + 3072;
    float* mean3 = mrs + 4096;   float* rs3 = mrs + 5120;

    // ---- setup ----
    hipMemsetAsync(deg, 0, (size_t)3*NNODES*4, stream);
    k_deg_cnt<<<NE/256, 256, 0, stream>>>(row, ew, deg, cnt);
    k_dinv<<<NNODES/256, 256, 0, stream>>>(deg, dinv);
    k_scan<<<1, 1024, 0, stream>>>(cnt, rowptr);
    k_fill<<<NE/256, 256, 0, stream>>>(row, col, ew, dinv, rowptr, fillc, ecol, ea);
    k_packB<<<24, 256, 0, stream>>>(W1, 256, 12, 256, 0, Bp1);
    k_packB<<<6, 256, 0, stream>>>(W2, 64, 12, 64, 0, Bp2);
    k_packB<<<24, 256, 0, stream>>>(W3, 64, 16, 192, 1, Bp3);

    // ---- layer 1: 256 -> 64 (Za=y0, Zb=u1, Zc=u2, node-major) ----
    k_gemm1<<<NNODES/32, 256, 0, stream>>>(x, Bp1, Za, Zb, Zc);
    k_prop<<<NNODES/8, 256, 0, stream>>>(rowptr, ecol, ea, Zc, Zb, 1.f, Zb, -2.f, nullptr);      // z = u1 - 2S(u2)
    k_prop<<<NNODES/8, 256, 0, stream>>>(rowptr, ecol, ea, Zb, Za, 1.f, Za, -1.f, Pbig);         // y = y0 - S(z) + stats
    k_redgen<<<dim3(2,512), 256, 0, stream>>>(Pbig, PPa, 512, 12);
    k_redgen<<<dim3(2,32), 256, 0, stream>>>(PPa, PPb, 512, 16);
    k_redfin<<<1, 256, 0, stream>>>(PPb, 512, 32, 64, mean1, rs1);
    k_normrelu<<<MTOT*64/2048, 256, 0, stream>>>(Za, mean1, rs1, Zc);                            // X2 = Zc

    // ---- layer 2: 64 -> 64 ----
    k_gemm2<<<MTOT/128, 256, 0, stream>>>(Zc, Bp2, Za, Zb, Zd);
    k_prop<<<NNODES/8, 256, 0, stream>>>(rowptr, ecol, ea, Zd, Zb, 1.f, Zb, -2.f, nullptr);
    k_prop<<<NNODES/8, 256, 0, stream>>>(rowptr, ecol, ea, Zb, Za, 1.f, Za, -1.f, Pbig);
    k_redgen<<<dim3(2,512), 256, 0, stream>>>(Pbig, PPa, 512, 12);
    k_redgen<<<dim3(2,32), 256, 0, stream>>>(PPa, PPb, 512, 16);
    k_redfin<<<1, 256, 0, stream>>>(PPb, 512, 32, 64, mean2, rs2);
    k_normrelu<<<MTOT*64/2048, 256, 0, stream>>>(Za, mean2, rs2, Zc);                            // X3 = Zc

    // ---- layer 3: 64 -> 256 (propagate in 64-dim input space) ----
    k_prop<<<NNODES/8, 256, 0, stream>>>(rowptr, ecol, ea, Zc, (const ushort*)nullptr, 0.f, Za, -1.f, nullptr); // T1
    k_prop<<<NNODES/8, 256, 0, stream>>>(rowptr, ecol, ea, Za, Zc, -1.f, Zb, -2.f, nullptr);                    // T2
    k_gemm3<<<MTOT/128, 256, 0, stream>>>(Zc, Za, Zb, Bp3, Ybf, Pbig);
    k_redgen<<<dim3(8,256), 256, 0, stream>>>(Pbig, PPa, 2048, 6);
    k_redgen<<<dim3(8,16), 256, 0, stream>>>(PPa, PPb, 2048, 16);
    k_redfin<<<4, 256, 0, stream>>>(PPb, 2048, 16, 256, mean3, rs3);
    k_final<<<MTOT/8, 256, 0, stream>>>(Ybf, x, mean3, rs3, (float*)d_out);
}

// Round 5
// 703.075 us; speedup vs baseline: 1.3527x; 1.0197x over previous
//
#include <hip/hip_runtime.h>

#define NNODES 49152
#define NB 4
#define NE 393216
#define MTOT (NB*NNODES)
#define EPS 1e-5f

typedef __attribute__((ext_vector_type(8))) short s8v;   // 8 x bf16 (raw)
typedef __attribute__((ext_vector_type(4))) float f32x4;

__device__ inline float b2f(ushort u){ union{uint i; float f;} v; v.i = ((uint)u)<<16; return v.f; }
__device__ inline ushort f2b(float f){ union{float f; uint i;} v; v.f=f; uint r = v.i + 0x7fff + ((v.i>>16)&1); return (ushort)(r>>16); }

// ---------------- setup kernels ----------------
__global__ __launch_bounds__(256) void k_deg_cnt(const int* __restrict__ row,
    const float* __restrict__ w, float* __restrict__ deg, int* __restrict__ cnt)
{
    int e = blockIdx.x*256 + threadIdx.x;
    if (e >= NE) return;
    int r = row[e];
    atomicAdd(&deg[r], w[e]);
    atomicAdd(&cnt[r], 1);
}

__global__ __launch_bounds__(256) void k_dinv(const float* __restrict__ deg, float* __restrict__ dinv)
{
    int i = blockIdx.x*256 + threadIdx.x;
    if (i >= NNODES) return;
    float d = deg[i];
    dinv[i] = (d > 0.0f) ? rsqrtf(fmaxf(d, EPS)) : 0.0f;
}

__global__ __launch_bounds__(1024) void k_scan(const int* __restrict__ cnt, int* __restrict__ rowptr)
{
    __shared__ int ssum[1024];
    const int CH = NNODES/1024; // 48
    int t = threadIdx.x;
    int base = t*CH;
    int loc[CH];
    int s = 0;
    #pragma unroll
    for (int i = 0; i < CH; ++i) { loc[i] = s; s += cnt[base+i]; }
    ssum[t] = s;
    __syncthreads();
    for (int off = 1; off < 1024; off <<= 1) {
        int v = ssum[t];
        int add = (t >= off) ? ssum[t-off] : 0;
        __syncthreads();
        ssum[t] = v + add;
        __syncthreads();
    }
    int prefix = (t == 0) ? 0 : ssum[t-1];
    #pragma unroll
    for (int i = 0; i < CH; ++i) rowptr[base+i] = prefix + loc[i];
    if (t == 0) rowptr[NNODES] = ssum[1023];
}

__global__ __launch_bounds__(256) void k_fill(const int* __restrict__ row, const int* __restrict__ col,
    const float* __restrict__ w, const float* __restrict__ dinv,
    const int* __restrict__ rowptr, int* __restrict__ fill,
    int* __restrict__ ecol, float* __restrict__ ea)
{
    int e = blockIdx.x*256 + threadIdx.x;
    if (e >= NE) return;
    int r = row[e], c = col[e];
    int pos = rowptr[r] + atomicAdd(&fill[r], 1);
    ecol[pos] = c;
    ea[pos] = w[e] * dinv[r] * dinv[c];
}

// ---------------- pack B into MFMA fragment order (bf16) ----------------
__global__ __launch_bounds__(256) void k_packB(const float* __restrict__ W, int Fin, int NF, int K,
    int mode, ushort* __restrict__ out)
{
    int t = blockIdx.x*256 + threadIdx.x;
    int lane = t & 63;
    int fid = t >> 6;
    if (fid >= (K/32)*NF) return;
    int kb = fid / NF, nb = fid % NF;
    int kbase = kb*32 + ((lane>>4)<<3);
    int n0 = nb*16 + (lane&15);
    #pragma unroll
    for (int j = 0; j < 8; ++j) {
        int kk = kbase + j;
        float v;
        if (mode == 0) {
            if (n0 < 64)       v = W[kk*64 + n0] - W[2*Fin*64 + kk*64 + n0];
            else if (n0 < 128) v = W[Fin*64 + kk*64 + (n0-64)];
            else               v = W[2*Fin*64 + kk*64 + (n0-128)];
        } else {
            v = W[(kk>>6)*64*256 + (kk&63)*256 + n0];
        }
        out[((long)fid*64 + lane)*8 + j] = f2b(v);
    }
}

// swizzle key: spreads 16-el column groups across banks keyed on row bits 0-5
__device__ inline int swz(int r){ return (((r>>2) ^ (r>>4) ^ r) & 3) << 4; }

// ---------------- GEMM1: fp32 x[b*N+n][256] @ Bp1 -> 3 bf16 node-major [n*4+b][64] ----------------
// grid over nodes (32/block); wave w handles batch w; block tile = dense rows [bid*128, +128)
__global__ __launch_bounds__(256) void k_gemm1(const float* __restrict__ A,
    const ushort* __restrict__ Bp, ushort* __restrict__ C0, ushort* __restrict__ C1, ushort* __restrict__ C2)
{
    __shared__ ushort btile[128*72];
    int tid = threadIdx.x;
    int w = tid >> 6, l = tid & 63;
    int lr = l & 15, kg = l >> 4;
    int n0 = blockIdx.x * 32;
    long rowbase = (long)blockIdx.x * 128;
    f32x4 acc[2][12];
    #pragma unroll
    for (int rf = 0; rf < 2; ++rf)
        #pragma unroll
        for (int nb = 0; nb < 12; ++nb) acc[rf][nb] = (f32x4){0.f,0.f,0.f,0.f};

    for (int kt = 0; kt < 256; kt += 32) {
        s8v afr[2];
        #pragma unroll
        for (int rf = 0; rf < 2; ++rf) {
            long rowg = (long)w*NNODES + n0 + rf*16 + lr;
            const float* af = A + rowg*256 + kt + (kg<<3);
            float4 v0 = *(const float4*)af;
            float4 v1 = *(const float4*)(af + 4);
            s8v fr;
            fr[0]=(short)f2b(v0.x); fr[1]=(short)f2b(v0.y); fr[2]=(short)f2b(v0.z); fr[3]=(short)f2b(v0.w);
            fr[4]=(short)f2b(v1.x); fr[5]=(short)f2b(v1.y); fr[6]=(short)f2b(v1.z); fr[7]=(short)f2b(v1.w);
            afr[rf] = fr;
        }
        const ushort* bb = Bp + ((long)(kt>>5)*12)*512 + l*8;
        #pragma unroll
        for (int nb = 0; nb < 12; ++nb) {
            s8v bfr = *(const s8v*)(bb + nb*512);
            acc[0][nb] = __builtin_amdgcn_mfma_f32_16x16x32_bf16(afr[0], bfr, acc[0][nb], 0, 0, 0);
            acc[1][nb] = __builtin_amdgcn_mfma_f32_16x16x32_bf16(afr[1], bfr, acc[1][nb], 0, 0, 0);
        }
    }
    // LDS-staged epilogue, one output array at a time
    for (int arr = 0; arr < 3; ++arr) {
        __syncthreads();
        #pragma unroll
        for (int rf = 0; rf < 2; ++rf)
            #pragma unroll
            for (int j = 0; j < 4; ++j)
                #pragma unroll
                for (int i = 0; i < 4; ++i) {
                    int lrow = (rf*16 + kg*4 + i)*4 + w;
                    int e = (j*16 + lr) ^ swz(lrow);
                    btile[lrow*72 + e] = f2b(acc[rf][arr*4 + j][i]);
                }
        __syncthreads();
        ushort* arrp = (arr == 0) ? C0 : ((arr == 1) ? C1 : C2);
        #pragma unroll
        for (int it = 0; it < 4; ++it) {
            int r = it*32 + (tid >> 3);
            int c = (tid & 7)*8;
            s8v v = *(const s8v*)(btile + r*72 + (c ^ swz(r)));
            *(s8v*)(arrp + (rowbase + r)*64 + c) = v;
        }
    }
}

// ---------------- GEMM2: bf16 node-major X[r][64] @ Bp2 -> 3 bf16 node-major [r][64] ----------------
__global__ __launch_bounds__(256) void k_gemm2(const ushort* __restrict__ A,
    const ushort* __restrict__ Bp, ushort* __restrict__ C0, ushort* __restrict__ C1, ushort* __restrict__ C2)
{
    __shared__ ushort btile[128*72];
    int tid = threadIdx.x;
    int w = tid >> 6, l = tid & 63;
    int lr = l & 15, kg = l >> 4;
    long rb = (long)blockIdx.x * 128;
    f32x4 acc[2][12];
    #pragma unroll
    for (int rf = 0; rf < 2; ++rf)
        #pragma unroll
        for (int nb = 0; nb < 12; ++nb) acc[rf][nb] = (f32x4){0.f,0.f,0.f,0.f};

    #pragma unroll
    for (int kt = 0; kt < 64; kt += 32) {
        s8v afr[2];
        #pragma unroll
        for (int rf = 0; rf < 2; ++rf) {
            long rg = rb + w*32 + rf*16 + lr;
            afr[rf] = *(const s8v*)(A + rg*64 + kt + (kg<<3));
        }
        const ushort* bb = Bp + ((long)(kt>>5)*12)*512 + l*8;
        #pragma unroll
        for (int nb = 0; nb < 12; ++nb) {
            s8v bfr = *(const s8v*)(bb + nb*512);
            acc[0][nb] = __builtin_amdgcn_mfma_f32_16x16x32_bf16(afr[0], bfr, acc[0][nb], 0, 0, 0);
            acc[1][nb] = __builtin_amdgcn_mfma_f32_16x16x32_bf16(afr[1], bfr, acc[1][nb], 0, 0, 0);
        }
    }
    for (int arr = 0; arr < 3; ++arr) {
        __syncthreads();
        #pragma unroll
        for (int rf = 0; rf < 2; ++rf)
            #pragma unroll
            for (int j = 0; j < 4; ++j)
                #pragma unroll
                for (int i = 0; i < 4; ++i) {
                    int lrow = w*32 + rf*16 + kg*4 + i;
                    int e = (j*16 + lr) ^ swz(lrow);
                    btile[lrow*72 + e] = f2b(acc[rf][arr*4 + j][i]);
                }
        __syncthreads();
        ushort* arrp = (arr == 0) ? C0 : ((arr == 1) ? C1 : C2);
        #pragma unroll
        for (int it = 0; it < 4; ++it) {
            int r = it*32 + (tid >> 3);
            int c = (tid & 7)*8;
            s8v v = *(const s8v*)(btile + r*72 + (c ^ swz(r)));
            *(s8v*)(arrp + (rb + r)*64 + c) = v;
        }
    }
}

// ---------------- GEMM3: 3 bf16 node-major parts (K=192) -> bf16 Ybf[r][256] + fused stats ----------------
__global__ __launch_bounds__(256) void k_gemm3(const ushort* __restrict__ A0,
    const ushort* __restrict__ A1, const ushort* __restrict__ A2,
    const ushort* __restrict__ Bp, ushort* __restrict__ C, float* __restrict__ Pst)
{
    __shared__ float smemf[8704];                  // 34816 B: tiles (4x16x272 ushort) / stats (2x16KB)
    int tid = threadIdx.x;
    int w = tid >> 6, l = tid & 63;
    int lr = l & 15, kg = l >> 4;
    long rb = (long)blockIdx.x * 128;
    f32x4 acc[2][16];
    #pragma unroll
    for (int rf = 0; rf < 2; ++rf)
        #pragma unroll
        for (int nb = 0; nb < 16; ++nb) acc[rf][nb] = (f32x4){0.f,0.f,0.f,0.f};

    for (int kt = 0; kt < 192; kt += 32) {
        int part = kt >> 6, kc = kt & 63;
        const ushort* Ap = (part == 0) ? A0 : ((part == 1) ? A1 : A2);
        s8v afr[2];
        #pragma unroll
        for (int rf = 0; rf < 2; ++rf) {
            long rg = rb + w*32 + rf*16 + lr;
            afr[rf] = *(const s8v*)(Ap + rg*64 + kc + (kg<<3));
        }
        const ushort* bb = Bp + ((long)(kt>>5)*16)*512 + l*8;
        #pragma unroll
        for (int nb = 0; nb < 16; ++nb) {
            s8v bfr = *(const s8v*)(bb + nb*512);
            acc[0][nb] = __builtin_amdgcn_mfma_f32_16x16x32_bf16(afr[0], bfr, acc[0][nb], 0, 0, 0);
            acc[1][nb] = __builtin_amdgcn_mfma_f32_16x16x32_bf16(afr[1], bfr, acc[1][nb], 0, 0, 0);
        }
    }
    // per-wave LDS-staged coalesced C write (rows rb+w*32..+32, contiguous)
    ushort* tile = (ushort*)smemf + w*4352;        // 16 rows x 272
    #pragma unroll
    for (int rf = 0; rf < 2; ++rf) {
        #pragma unroll
        for (int nb = 0; nb < 16; ++nb)
            #pragma unroll
            for (int i = 0; i < 4; ++i) {
                int r = kg*4 + i;
                tile[r*272 + ((nb*16 + lr) ^ swz(r))] = f2b(acc[rf][nb][i]);
            }
        #pragma unroll
        for (int it = 0; it < 8; ++it) {
            int r = it*2 + (l >> 5);
            int c = (l & 31)*8;
            s8v v = *(const s8v*)(tile + r*272 + (c ^ swz(r)));
            *(s8v*)(C + (rb + w*32 + rf*16 + r)*256 + c) = v;
        }
    }
    __syncthreads();
    // fused per-block channel stats (batch = i since all row terms are %4==0)
    float* Ls = smemf;            // [4][4][256]
    float* Lq = smemf + 4096;
    #pragma unroll
    for (int nb = 0; nb < 16; ++nb) {
        #pragma unroll
        for (int i = 0; i < 4; ++i) {
            float x0 = acc[0][nb][i], x1 = acc[1][nb][i];
            float s = x0 + x1;
            float q = x0*x0 + x1*x1;
            s += __shfl_xor(s, 16); s += __shfl_xor(s, 32);
            q += __shfl_xor(q, 16); q += __shfl_xor(q, 32);
            if (kg == 0) { Ls[(w*4 + i)*256 + nb*16 + lr] = s; Lq[(w*4 + i)*256 + nb*16 + lr] = q; }
        }
    }
    __syncthreads();
    int t = tid;
    #pragma unroll
    for (int b = 0; b < 4; ++b) {
        float S = Ls[b*256 + t] + Ls[(4+b)*256 + t] + Ls[(8+b)*256 + t] + Ls[(12+b)*256 + t];
        float Q = Lq[b*256 + t] + Lq[(4+b)*256 + t] + Lq[(8+b)*256 + t] + Lq[(12+b)*256 + t];
        Pst[(long)blockIdx.x*2048 + b*256 + t] = S;
        Pst[(long)blockIdx.x*2048 + 1024 + b*256 + t] = Q;
    }
}

// ---------------- propagation (CSR gather, node-major bf16, 4-deep pipelined) ----------------
__global__ __launch_bounds__(256) void k_prop(
    const int* __restrict__ rowptr, const int* __restrict__ ecol, const float* __restrict__ ea,
    const ushort* __restrict__ src, const ushort* __restrict__ basep, float beta,
    ushort* __restrict__ dst, float alpha, float* __restrict__ Pst)
{
    int g = blockIdx.x*8 + (threadIdx.x >> 5);
    int sub = threadIdx.x & 31;
    int e0 = rowptr[g], e1 = rowptr[g+1];
    float acc[8];
    #pragma unroll
    for (int j = 0; j < 8; ++j) acc[j] = 0.f;
    int e = e0;
    for (; e + 4 <= e1; e += 4) {
        int c0 = ecol[e], c1 = ecol[e+1], c2 = ecol[e+2], c3 = ecol[e+3];
        float a0 = ea[e], a1 = ea[e+1], a2 = ea[e+2], a3 = ea[e+3];
        s8v v0 = *(const s8v*)(src + (long)c0*256 + sub*8);
        s8v v1 = *(const s8v*)(src + (long)c1*256 + sub*8);
        s8v v2 = *(const s8v*)(src + (long)c2*256 + sub*8);
        s8v v3 = *(const s8v*)(src + (long)c3*256 + sub*8);
        #pragma unroll
        for (int j = 0; j < 8; ++j)
            acc[j] += a0*b2f((ushort)v0[j]) + a1*b2f((ushort)v1[j])
                    + a2*b2f((ushort)v2[j]) + a3*b2f((ushort)v3[j]);
    }
    for (; e < e1; ++e) {
        int c = ecol[e]; float a = ea[e];
        s8v v = *(const s8v*)(src + (long)c*256 + sub*8);
        #pragma unroll
        for (int j = 0; j < 8; ++j) acc[j] += a*b2f((ushort)v[j]);
    }
    float o[8];
    if (basep) {
        s8v bv = *(const s8v*)(basep + (long)g*256 + sub*8);
        #pragma unroll
        for (int j = 0; j < 8; ++j) o[j] = alpha*acc[j] + beta*b2f((ushort)bv[j]);
    } else {
        #pragma unroll
        for (int j = 0; j < 8; ++j) o[j] = alpha*acc[j];
    }
    s8v ov;
    #pragma unroll
    for (int j = 0; j < 8; ++j) ov[j] = (short)f2b(o[j]);
    *(s8v*)(dst + (long)g*256 + sub*8) = ov;

    if (Pst) {
        __shared__ float Ls[8][256];
        __shared__ float Lq[8][256];
        int grp = threadIdx.x >> 5;
        #pragma unroll
        for (int j = 0; j < 8; ++j) {
            Ls[grp][sub*8 + j] = o[j];
            Lq[grp][sub*8 + j] = o[j]*o[j];
        }
        __syncthreads();
        int t = threadIdx.x;
        float s = 0.f, q = 0.f;
        #pragma unroll
        for (int k = 0; k < 8; ++k) { s += Ls[k][t]; q += Lq[k][t]; }
        Pst[(long)blockIdx.x*512 + t] = s;
        Pst[(long)blockIdx.x*512 + 256 + t] = q;
    }
}

// ---------------- tree reduction (atomic-free) ----------------
__global__ __launch_bounds__(256) void k_redgen(const float* __restrict__ in, float* __restrict__ out,
    int S, int nin)
{
    int j = blockIdx.x*256 + threadIdx.x;
    int o = blockIdx.y;
    long base = (long)o*nin*S + j;
    float s = 0.f;
    for (int k = 0; k < nin; ++k) s += in[base + (long)k*S];
    out[(long)o*S + j] = s;
}

__global__ __launch_bounds__(256) void k_redfin(const float* __restrict__ in, int S, int nin, int Cw,
    float* __restrict__ mean, float* __restrict__ rs)
{
    int half = S >> 1;
    int j = blockIdx.x*256 + threadIdx.x;
    if (j >= half) return;
    float s = 0.f, q = 0.f;
    for (int k = 0; k < nin; ++k) {
        s += in[(long)k*S + j];
        q += in[(long)k*S + half + j];
    }
    float m = s / (float)NNODES;
    float v = q / (float)NNODES - m*m;
    int b = j / Cw, c = j - b*Cw;
    mean[b*256 + c] = m;
    rs[b*256 + c] = rsqrtf(v + EPS);
}

// ---------------- norm-relu (node-major [MTOT*64] bf16) ----------------
__global__ __launch_bounds__(256) void k_normrelu(const ushort* __restrict__ y,
    const float* __restrict__ mean, const float* __restrict__ rs, ushort* __restrict__ X)
{
    int t = threadIdx.x;
    long e = (long)blockIdx.x*2048 + t*8;
    int b = (t>>3)&3, c0 = (t&7)*8;
    s8v v = *(const s8v*)(y + e);
    float4 m0 = *(const float4*)(mean + b*256 + c0);
    float4 m1 = *(const float4*)(mean + b*256 + c0 + 4);
    float4 r0 = *(const float4*)(rs + b*256 + c0);
    float4 r1 = *(const float4*)(rs + b*256 + c0 + 4);
    float mm[8] = {m0.x,m0.y,m0.z,m0.w,m1.x,m1.y,m1.z,m1.w};
    float rr[8] = {r0.x,r0.y,r0.z,r0.w,r1.x,r1.y,r1.z,r1.w};
    s8v o;
    #pragma unroll
    for (int j = 0; j < 8; ++j) o[j] = (short)f2b(fmaxf((b2f((ushort)v[j]) - mm[j])*rr[j], 0.f));
    *(s8v*)(X + e) = o;
}

// ---------------- final: out[(b*N+n)*256+c] = relu((Ybf[(n*4+b)*256+c]-mean)*rs) + x ----------------
__global__ __launch_bounds__(256) void k_final(const ushort* __restrict__ Ybf,
    const float* __restrict__ x, const float* __restrict__ mean, const float* __restrict__ rs,
    float* __restrict__ out)
{
    int t = threadIdx.x;
    long orow = (long)blockIdx.x*8 + (t>>5);
    int c0 = (t&31)*8;
    int b = (int)(orow / NNODES);
    int n = (int)(orow - (long)b*NNODES);
    s8v v = *(const s8v*)(Ybf + ((long)n*4 + b)*256 + c0);
    float4 m0 = *(const float4*)(mean + b*256 + c0);
    float4 m1 = *(const float4*)(mean + b*256 + c0 + 4);
    float4 r0 = *(const float4*)(rs + b*256 + c0);
    float4 r1 = *(const float4*)(rs + b*256 + c0 + 4);
    float mm[8] = {m0.x,m0.y,m0.z,m0.w,m1.x,m1.y,m1.z,m1.w};
    float rr[8] = {r0.x,r0.y,r0.z,r0.w,r1.x,r1.y,r1.z,r1.w};
    const float* xp = x + orow*256 + c0;
    float* op = out + orow*256 + c0;
    #pragma unroll
    for (int j = 0; j < 8; ++j)
        op[j] = fmaxf((b2f((ushort)v[j]) - mm[j])*rr[j], 0.f) + xp[j];
}

extern "C" void kernel_launch(void* const* d_in, const int* in_sizes, int n_in,
                              void* d_out, int out_size, void* d_ws, size_t ws_size,
                              hipStream_t stream)
{
    const float* x  = (const float*)d_in[0];
    const int*   ei = (const int*)d_in[1];
    const float* ew = (const float*)d_in[2];
    const float* W1 = (const float*)d_in[3];
    const float* W2 = (const float*)d_in[5];
    const float* W3 = (const float*)d_in[7];
    const int* row = ei;
    const int* col = ei + NE;

    char* p = (char*)d_ws;
    size_t used = 0;
    auto alloc = [&](size_t bytes) -> void* {
        void* r = p + used;
        used += (bytes + 1023) & ~(size_t)1023;
        return r;
    };
    float* deg   = (float*)alloc((size_t)3*NNODES*4);     // deg | cnt | fill (zeroed)
    int*   cnt   = (int*)(deg + NNODES);
    int*   fillc = (int*)(deg + 2*NNODES);
    float* dinv  = (float*)alloc((size_t)NNODES*4);
    int*   rowptr= (int*)alloc((size_t)(NNODES+1)*4);
    int*   ecol  = (int*)alloc((size_t)NE*4);
    float* ea    = (float*)alloc((size_t)NE*4);
    float* mrs   = (float*)alloc((size_t)3*2*1024*4);     // per layer: mean[1024] | rs[1024]
    ushort* Bp1  = (ushort*)alloc((size_t)256*192*2);
    ushort* Bp2  = (ushort*)alloc((size_t)64*192*2);
    ushort* Bp3  = (ushort*)alloc((size_t)192*256*2);
    ushort* Za   = (ushort*)alloc((size_t)MTOT*64*2);
    ushort* Zb   = (ushort*)alloc((size_t)MTOT*64*2);
    ushort* Zc   = (ushort*)alloc((size_t)MTOT*64*2);
    ushort* Zd   = (ushort*)alloc((size_t)MTOT*64*2);
    float* Pbig  = (float*)alloc((size_t)6144*512*4);     // 12.6 MB (also holds 1536x2048)
    float* PPa   = (float*)alloc((size_t)256*2048*4);     // 2 MB
    float* PPb   = (float*)alloc((size_t)16*2048*4);      // 128 KB
    ushort* Ybf  = (ushort*)alloc((size_t)MTOT*256*2);    // 100 MB
    if (ws_size < used) return;

    float* mean1 = mrs;          float* rs1 = mrs + 1024;
    float* mean2 = mrs + 2048;   float* rs2 = mrs + 3072;
    float* mean3 = mrs + 4096;   float* rs3 = mrs + 5120;

    // ---- setup ----
    hipMemsetAsync(deg, 0, (size_t)3*NNODES*4, stream);
    k_deg_cnt<<<NE/256, 256, 0, stream>>>(row, ew, deg, cnt);
    k_dinv<<<NNODES/256, 256, 0, stream>>>(deg, dinv);
    k_scan<<<1, 1024, 0, stream>>>(cnt, rowptr);
    k_fill<<<NE/256, 256, 0, stream>>>(row, col, ew, dinv, rowptr, fillc, ecol, ea);
    k_packB<<<24, 256, 0, stream>>>(W1, 256, 12, 256, 0, Bp1);
    k_packB<<<6, 256, 0, stream>>>(W2, 64, 12, 64, 0, Bp2);
    k_packB<<<24, 256, 0, stream>>>(W3, 64, 16, 192, 1, Bp3);

    // ---- layer 1: 256 -> 64 (Za=y0, Zb=u1, Zc=u2, node-major) ----
    k_gemm1<<<NNODES/32, 256, 0, stream>>>(x, Bp1, Za, Zb, Zc);
    k_prop<<<NNODES/8, 256, 0, stream>>>(rowptr, ecol, ea, Zc, Zb, 1.f, Zb, -2.f, nullptr);      // z = u1 - 2S(u2)
    k_prop<<<NNODES/8, 256, 0, stream>>>(rowptr, ecol, ea, Zb, Za, 1.f, Za, -1.f, Pbig);         // y = y0 - S(z) + stats
    k_redgen<<<dim3(2,512), 256, 0, stream>>>(Pbig, PPa, 512, 12);
    k_redgen<<<dim3(2,32), 256, 0, stream>>>(PPa, PPb, 512, 16);
    k_redfin<<<1, 256, 0, stream>>>(PPb, 512, 32, 64, mean1, rs1);
    k_normrelu<<<MTOT*64/2048, 256, 0, stream>>>(Za, mean1, rs1, Zc);                            // X2 = Zc

    // ---- layer 2: 64 -> 64 ----
    k_gemm2<<<MTOT/128, 256, 0, stream>>>(Zc, Bp2, Za, Zb, Zd);
    k_prop<<<NNODES/8, 256, 0, stream>>>(rowptr, ecol, ea, Zd, Zb, 1.f, Zb, -2.f, nullptr);
    k_prop<<<NNODES/8, 256, 0, stream>>>(rowptr, ecol, ea, Zb, Za, 1.f, Za, -1.f, Pbig);
    k_redgen<<<dim3(2,512), 256, 0, stream>>>(Pbig, PPa, 512, 12);
    k_redgen<<<dim3(2,32), 256, 0, stream>>>(PPa, PPb, 512, 16);
    k_redfin<<<1, 256, 0, stream>>>(PPb, 512, 32, 64, mean2, rs2);
    k_normrelu<<<MTOT*64/2048, 256, 0, stream>>>(Za, mean2, rs2, Zc);                            // X3 = Zc

    // ---- layer 3: 64 -> 256 (propagate in 64-dim input space) ----
    k_prop<<<NNODES/8, 256, 0, stream>>>(rowptr, ecol, ea, Zc, (const ushort*)nullptr, 0.f, Za, -1.f, nullptr); // T1
    k_prop<<<NNODES/8, 256, 0, stream>>>(rowptr, ecol, ea, Za, Zc, -1.f, Zb, -2.f, nullptr);                    // T2
    k_gemm3<<<MTOT/128, 256, 0, stream>>>(Zc, Za, Zb, Bp3, Ybf, Pbig);
    k_redgen<<<dim3(8,256), 256, 0, stream>>>(Pbig, PPa, 2048, 6);
    k_redgen<<<dim3(8,16), 256, 0, stream>>>(PPa, PPb, 2048, 16);
    k_redfin<<<4, 256, 0, stream>>>(PPb, 2048, 16, 256, mean3, rs3);
    k_final<<<MTOT/8, 256, 0, stream>>>(Ybf, x, mean3, rs3, (float*)d_out);
}

// Round 6
// 618.884 us; speedup vs baseline: 1.5367x; 1.1360x over previous
//
#include <hip/hip_runtime.h>

#define NNODES 49152
#define NB 4
#define NE 393216
#define MTOT (NB*NNODES)
#define EPS 1e-5f

typedef __attribute__((ext_vector_type(8))) short s8v;   // 8 x bf16 (raw)
typedef __attribute__((ext_vector_type(4))) float f32x4;

__device__ inline float b2f(ushort u){ union{uint i; float f;} v; v.i = ((uint)u)<<16; return v.f; }
__device__ inline ushort f2b(float f){ union{float f; uint i;} v; v.f=f; uint r = v.i + 0x7fff + ((v.i>>16)&1); return (ushort)(r>>16); }

// ---------------- setup kernels ----------------
__global__ __launch_bounds__(256) void k_deg_cnt(const int* __restrict__ row,
    const float* __restrict__ w, float* __restrict__ deg, int* __restrict__ cnt)
{
    int e = blockIdx.x*256 + threadIdx.x;
    if (e >= NE) return;
    int r = row[e];
    atomicAdd(&deg[r], w[e]);
    atomicAdd(&cnt[r], 1);
}

__global__ __launch_bounds__(256) void k_dinv(const float* __restrict__ deg, float* __restrict__ dinv)
{
    int i = blockIdx.x*256 + threadIdx.x;
    if (i >= NNODES) return;
    float d = deg[i];
    dinv[i] = (d > 0.0f) ? rsqrtf(fmaxf(d, EPS)) : 0.0f;
}

__global__ __launch_bounds__(1024) void k_scan(const int* __restrict__ cnt, int* __restrict__ rowptr)
{
    __shared__ int ssum[1024];
    const int CH = NNODES/1024; // 48
    int t = threadIdx.x;
    int base = t*CH;
    int loc[CH];
    int s = 0;
    #pragma unroll
    for (int i = 0; i < CH; ++i) { loc[i] = s; s += cnt[base+i]; }
    ssum[t] = s;
    __syncthreads();
    for (int off = 1; off < 1024; off <<= 1) {
        int v = ssum[t];
        int add = (t >= off) ? ssum[t-off] : 0;
        __syncthreads();
        ssum[t] = v + add;
        __syncthreads();
    }
    int prefix = (t == 0) ? 0 : ssum[t-1];
    #pragma unroll
    for (int i = 0; i < CH; ++i) rowptr[base+i] = prefix + loc[i];
    if (t == 0) rowptr[NNODES] = ssum[1023];
}

__global__ __launch_bounds__(256) void k_fill(const int* __restrict__ row, const int* __restrict__ col,
    const float* __restrict__ w, const float* __restrict__ dinv,
    const int* __restrict__ rowptr, int* __restrict__ fill,
    int* __restrict__ ecol, float* __restrict__ ea)
{
    int e = blockIdx.x*256 + threadIdx.x;
    if (e >= NE) return;
    int r = row[e], c = col[e];
    int pos = rowptr[r] + atomicAdd(&fill[r], 1);
    ecol[pos] = c;
    ea[pos] = w[e] * dinv[r] * dinv[c];
}

// ---------------- pack B into MFMA fragment order (bf16) ----------------
// chunk kb (K=32 slice) occupies contiguous NF*512 ushorts
__global__ __launch_bounds__(256) void k_packB(const float* __restrict__ W, int Fin, int NF, int K,
    int mode, ushort* __restrict__ out)
{
    int t = blockIdx.x*256 + threadIdx.x;
    int lane = t & 63;
    int fid = t >> 6;
    if (fid >= (K/32)*NF) return;
    int kb = fid / NF, nb = fid % NF;
    int kbase = kb*32 + ((lane>>4)<<3);
    int n0 = nb*16 + (lane&15);
    #pragma unroll
    for (int j = 0; j < 8; ++j) {
        int kk = kbase + j;
        float v;
        if (mode == 0) {
            if (n0 < 64)       v = W[kk*64 + n0] - W[2*Fin*64 + kk*64 + n0];
            else if (n0 < 128) v = W[Fin*64 + kk*64 + (n0-64)];
            else               v = W[2*Fin*64 + kk*64 + (n0-128)];
        } else {
            v = W[(kk>>6)*64*256 + (kk&63)*256 + n0];
        }
        out[((long)fid*64 + lane)*8 + j] = f2b(v);
    }
}

// ---------------- GEMM1: fp32 x[b*N+n][256] @ Bp1(LDS-staged) -> 3 bf16 node-major [n*4+b][64] ----------------
// block = 16 nodes x 4 batches (wave = batch); wave computes 16 rows x 192.
__global__ __launch_bounds__(256,3) void k_gemm1(const float* __restrict__ A,
    const ushort* __restrict__ Bp, ushort* __restrict__ C0, ushort* __restrict__ C1, ushort* __restrict__ C2)
{
    __shared__ ushort Bs[2][6144];   // 12 KB x2 (one K=32 chunk, NF=12)
    int tid = threadIdx.x;
    int w = tid >> 6, l = tid & 63;
    int lr = l & 15, kg = l >> 4;
    int n0 = blockIdx.x * 16;

    // A prefetch: 16 indep float4-pair loads, converted to bf16 frags as they land
    const float* ap = A + ((long)w*NNODES + n0 + lr)*256 + (kg<<3);
    s8v af[8];
    #pragma unroll
    for (int t = 0; t < 8; ++t) {
        float4 v0 = *(const float4*)(ap + t*32);
        float4 v1 = *(const float4*)(ap + t*32 + 4);
        s8v fr;
        fr[0]=(short)f2b(v0.x); fr[1]=(short)f2b(v0.y); fr[2]=(short)f2b(v0.z); fr[3]=(short)f2b(v0.w);
        fr[4]=(short)f2b(v1.x); fr[5]=(short)f2b(v1.y); fr[6]=(short)f2b(v1.z); fr[7]=(short)f2b(v1.w);
        af[t] = fr;
    }
    f32x4 acc[12];
    #pragma unroll
    for (int nb = 0; nb < 12; ++nb) acc[nb] = (f32x4){0.f,0.f,0.f,0.f};

    // stage chunk 0
    #pragma unroll
    for (int ps = 0; ps < 3; ++ps) {
        int off = ps*2048 + tid*8;
        *(s8v*)(&Bs[0][off]) = *(const s8v*)(Bp + off);
    }
    #pragma unroll
    for (int t = 0; t < 8; ++t) {
        __syncthreads();
        s8v stg[3];
        if (t < 7) {
            #pragma unroll
            for (int ps = 0; ps < 3; ++ps)
                stg[ps] = *(const s8v*)(Bp + (long)(t+1)*6144 + ps*2048 + tid*8);
        }
        const ushort* bb = &Bs[t&1][l*8];
        #pragma unroll
        for (int nb = 0; nb < 12; ++nb) {
            s8v bfr = *(const s8v*)(bb + nb*512);
            acc[nb] = __builtin_amdgcn_mfma_f32_16x16x32_bf16(af[t], bfr, acc[nb], 0, 0, 0);
        }
        if (t < 7) {
            #pragma unroll
            for (int ps = 0; ps < 3; ++ps)
                *(s8v*)(&Bs[(t+1)&1][ps*2048 + tid*8]) = stg[ps];
        }
    }
    // direct store: node n0+kg*4+i, node-major row = node*4 + w
    #pragma unroll
    for (int nb = 0; nb < 12; ++nb) {
        ushort* arr = (nb < 4) ? C0 : ((nb < 8) ? C1 : C2);
        int cc = (nb&3)*16 + lr;
        #pragma unroll
        for (int i = 0; i < 4; ++i) {
            long crow = (long)(n0 + kg*4 + i)*4 + w;
            arr[crow*64 + cc] = f2b(acc[nb][i]);
        }
    }
}

// ---------------- GEMM2: bf16 node-major X[r][64] @ Bp2(LDS) -> 3 bf16 node-major [r][64] ----------------
// block = 64 rows, wave = 16 rows; whole B (24 KB) staged once.
__global__ __launch_bounds__(256,3) void k_gemm2(const ushort* __restrict__ A,
    const ushort* __restrict__ Bp, ushort* __restrict__ C0, ushort* __restrict__ C1, ushort* __restrict__ C2)
{
    __shared__ ushort Bs[12288];     // 24 KB = 2 chunks x 12 KB
    int tid = threadIdx.x;
    int w = tid >> 6, l = tid & 63;
    int lr = l & 15, kg = l >> 4;
    long rb = (long)blockIdx.x * 64;

    long arow = (rb + w*16 + lr)*64 + (kg<<3);
    s8v af0 = *(const s8v*)(A + arow);
    s8v af1 = *(const s8v*)(A + arow + 32);
    #pragma unroll
    for (int ps = 0; ps < 6; ++ps) {
        int off = ps*2048 + tid*8;
        *(s8v*)(&Bs[off]) = *(const s8v*)(Bp + off);
    }
    f32x4 acc[12];
    #pragma unroll
    for (int nb = 0; nb < 12; ++nb) acc[nb] = (f32x4){0.f,0.f,0.f,0.f};
    __syncthreads();
    #pragma unroll
    for (int t = 0; t < 2; ++t) {
        const ushort* bb = &Bs[t*6144 + l*8];
        s8v afr = t ? af1 : af0;
        #pragma unroll
        for (int nb = 0; nb < 12; ++nb) {
            s8v bfr = *(const s8v*)(bb + nb*512);
            acc[nb] = __builtin_amdgcn_mfma_f32_16x16x32_bf16(afr, bfr, acc[nb], 0, 0, 0);
        }
    }
    #pragma unroll
    for (int nb = 0; nb < 12; ++nb) {
        ushort* arr = (nb < 4) ? C0 : ((nb < 8) ? C1 : C2);
        int cc = (nb&3)*16 + lr;
        #pragma unroll
        for (int i = 0; i < 4; ++i) {
            long crow = rb + w*16 + kg*4 + i;
            arr[crow*64 + cc] = f2b(acc[nb][i]);
        }
    }
}

// ---------------- GEMM3: 3 bf16 node-major parts (K=192) @ Bp3(LDS dbuf) -> bf16 Ybf[r][256] + fused stats ----------------
// block = 64 rows, wave = 16 rows; batch of output row == acc index i.
__global__ __launch_bounds__(256,3) void k_gemm3(const ushort* __restrict__ A0,
    const ushort* __restrict__ A1, const ushort* __restrict__ A2,
    const ushort* __restrict__ Bp, ushort* __restrict__ C, float* __restrict__ Pst)
{
    __shared__ ushort Bs[2][8192];   // 16 KB x2; reused as 2x16KB float stats after loop
    int tid = threadIdx.x;
    int w = tid >> 6, l = tid & 63;
    int lr = l & 15, kg = l >> 4;
    long rb = (long)blockIdx.x * 64;

    long arow = (rb + w*16 + lr)*64 + (kg<<3);
    s8v ap[6];
    ap[0] = *(const s8v*)(A0 + arow); ap[1] = *(const s8v*)(A0 + arow + 32);
    ap[2] = *(const s8v*)(A1 + arow); ap[3] = *(const s8v*)(A1 + arow + 32);
    ap[4] = *(const s8v*)(A2 + arow); ap[5] = *(const s8v*)(A2 + arow + 32);
    f32x4 acc[16];
    #pragma unroll
    for (int nb = 0; nb < 16; ++nb) acc[nb] = (f32x4){0.f,0.f,0.f,0.f};

    #pragma unroll
    for (int ps = 0; ps < 4; ++ps) {
        int off = ps*2048 + tid*8;
        *(s8v*)(&Bs[0][off]) = *(const s8v*)(Bp + off);
    }
    #pragma unroll
    for (int t = 0; t < 6; ++t) {
        __syncthreads();
        s8v stg[4];
        if (t < 5) {
            #pragma unroll
            for (int ps = 0; ps < 4; ++ps)
                stg[ps] = *(const s8v*)(Bp + (long)(t+1)*8192 + ps*2048 + tid*8);
        }
        const ushort* bb = &Bs[t&1][l*8];
        #pragma unroll
        for (int nb = 0; nb < 16; ++nb) {
            s8v bfr = *(const s8v*)(bb + nb*512);
            acc[nb] = __builtin_amdgcn_mfma_f32_16x16x32_bf16(ap[t], bfr, acc[nb], 0, 0, 0);
        }
        if (t < 5) {
            #pragma unroll
            for (int ps = 0; ps < 4; ++ps)
                *(s8v*)(&Bs[(t+1)&1][ps*2048 + tid*8]) = stg[ps];
        }
    }
    // direct C store: row rb + w*16 + kg*4 + i, col nb*16+lr
    #pragma unroll
    for (int nb = 0; nb < 16; ++nb) {
        #pragma unroll
        for (int i = 0; i < 4; ++i) {
            long crow = rb + w*16 + kg*4 + i;
            C[crow*256 + nb*16 + lr] = f2b(acc[nb][i]);
        }
    }
    // fused stats: batch = i (row % 4 == i); reduce kg via shfl, waves via LDS
    __syncthreads();
    float* Ls = (float*)Bs;          // [16][256]
    float* Lq = Ls + 4096;
    #pragma unroll
    for (int nb = 0; nb < 16; ++nb) {
        #pragma unroll
        for (int i = 0; i < 4; ++i) {
            float s = acc[nb][i];
            float q = s*s;
            s += __shfl_xor(s, 16); s += __shfl_xor(s, 32);
            q += __shfl_xor(q, 16); q += __shfl_xor(q, 32);
            if (kg == 0) { Ls[(w*4 + i)*256 + nb*16 + lr] = s; Lq[(w*4 + i)*256 + nb*16 + lr] = q; }
        }
    }
    __syncthreads();
    #pragma unroll
    for (int b = 0; b < 4; ++b) {
        float S = Ls[b*256 + tid] + Ls[(4+b)*256 + tid] + Ls[(8+b)*256 + tid] + Ls[(12+b)*256 + tid];
        float Q = Lq[b*256 + tid] + Lq[(4+b)*256 + tid] + Lq[(8+b)*256 + tid] + Lq[(12+b)*256 + tid];
        Pst[(long)blockIdx.x*2048 + b*256 + tid] = S;
        Pst[(long)blockIdx.x*2048 + 1024 + b*256 + tid] = Q;
    }
}

// ---------------- propagation (CSR gather, node-major bf16, 4-deep pipelined) ----------------
__global__ __launch_bounds__(256) void k_prop(
    const int* __restrict__ rowptr, const int* __restrict__ ecol, const float* __restrict__ ea,
    const ushort* __restrict__ src, const ushort* __restrict__ basep, float beta,
    ushort* __restrict__ dst, float alpha, float* __restrict__ Pst)
{
    int g = blockIdx.x*8 + (threadIdx.x >> 5);
    int sub = threadIdx.x & 31;
    int e0 = rowptr[g], e1 = rowptr[g+1];
    float acc[8];
    #pragma unroll
    for (int j = 0; j < 8; ++j) acc[j] = 0.f;
    int e = e0;
    for (; e + 4 <= e1; e += 4) {
        int c0 = ecol[e], c1 = ecol[e+1], c2 = ecol[e+2], c3 = ecol[e+3];
        float a0 = ea[e], a1 = ea[e+1], a2 = ea[e+2], a3 = ea[e+3];
        s8v v0 = *(const s8v*)(src + (long)c0*256 + sub*8);
        s8v v1 = *(const s8v*)(src + (long)c1*256 + sub*8);
        s8v v2 = *(const s8v*)(src + (long)c2*256 + sub*8);
        s8v v3 = *(const s8v*)(src + (long)c3*256 + sub*8);
        #pragma unroll
        for (int j = 0; j < 8; ++j)
            acc[j] += a0*b2f((ushort)v0[j]) + a1*b2f((ushort)v1[j])
                    + a2*b2f((ushort)v2[j]) + a3*b2f((ushort)v3[j]);
    }
    for (; e < e1; ++e) {
        int c = ecol[e]; float a = ea[e];
        s8v v = *(const s8v*)(src + (long)c*256 + sub*8);
        #pragma unroll
        for (int j = 0; j < 8; ++j) acc[j] += a*b2f((ushort)v[j]);
    }
    float o[8];
    if (basep) {
        s8v bv = *(const s8v*)(basep + (long)g*256 + sub*8);
        #pragma unroll
        for (int j = 0; j < 8; ++j) o[j] = alpha*acc[j] + beta*b2f((ushort)bv[j]);
    } else {
        #pragma unroll
        for (int j = 0; j < 8; ++j) o[j] = alpha*acc[j];
    }
    s8v ov;
    #pragma unroll
    for (int j = 0; j < 8; ++j) ov[j] = (short)f2b(o[j]);
    *(s8v*)(dst + (long)g*256 + sub*8) = ov;

    if (Pst) {
        __shared__ float Ls[8][256];
        __shared__ float Lq[8][256];
        int grp = threadIdx.x >> 5;
        #pragma unroll
        for (int j = 0; j < 8; ++j) {
            Ls[grp][sub*8 + j] = o[j];
            Lq[grp][sub*8 + j] = o[j]*o[j];
        }
        __syncthreads();
        int t = threadIdx.x;
        float s = 0.f, q = 0.f;
        #pragma unroll
        for (int k = 0; k < 8; ++k) { s += Ls[k][t]; q += Lq[k][t]; }
        Pst[(long)blockIdx.x*512 + t] = s;
        Pst[(long)blockIdx.x*512 + 256 + t] = q;
    }
}

// ---------------- tree reduction (atomic-free) ----------------
__global__ __launch_bounds__(256) void k_redgen(const float* __restrict__ in, float* __restrict__ out,
    int S, int nin)
{
    int j = blockIdx.x*256 + threadIdx.x;
    int o = blockIdx.y;
    long base = (long)o*nin*S + j;
    float s = 0.f;
    for (int k = 0; k < nin; ++k) s += in[base + (long)k*S];
    out[(long)o*S + j] = s;
}

__global__ __launch_bounds__(256) void k_redfin(const float* __restrict__ in, int S, int nin, int Cw,
    float* __restrict__ mean, float* __restrict__ rs)
{
    int half = S >> 1;
    int j = blockIdx.x*256 + threadIdx.x;
    if (j >= half) return;
    float s = 0.f, q = 0.f;
    for (int k = 0; k < nin; ++k) {
        s += in[(long)k*S + j];
        q += in[(long)k*S + half + j];
    }
    float m = s / (float)NNODES;
    float v = q / (float)NNODES - m*m;
    int b = j / Cw, c = j - b*Cw;
    mean[b*256 + c] = m;
    rs[b*256 + c] = rsqrtf(v + EPS);
}

// ---------------- norm-relu (node-major [MTOT*64] bf16) ----------------
__global__ __launch_bounds__(256) void k_normrelu(const ushort* __restrict__ y,
    const float* __restrict__ mean, const float* __restrict__ rs, ushort* __restrict__ X)
{
    int t = threadIdx.x;
    long e = (long)blockIdx.x*2048 + t*8;
    int b = (t>>3)&3, c0 = (t&7)*8;
    s8v v = *(const s8v*)(y + e);
    float4 m0 = *(const float4*)(mean + b*256 + c0);
    float4 m1 = *(const float4*)(mean + b*256 + c0 + 4);
    float4 r0 = *(const float4*)(rs + b*256 + c0);
    float4 r1 = *(const float4*)(rs + b*256 + c0 + 4);
    float mm[8] = {m0.x,m0.y,m0.z,m0.w,m1.x,m1.y,m1.z,m1.w};
    float rr[8] = {r0.x,r0.y,r0.z,r0.w,r1.x,r1.y,r1.z,r1.w};
    s8v o;
    #pragma unroll
    for (int j = 0; j < 8; ++j) o[j] = (short)f2b(fmaxf((b2f((ushort)v[j]) - mm[j])*rr[j], 0.f));
    *(s8v*)(X + e) = o;
}

// ---------------- final: out[(b*N+n)*256+c] = relu((Ybf[(n*4+b)*256+c]-mean)*rs) + x ----------------
__global__ __launch_bounds__(256) void k_final(const ushort* __restrict__ Ybf,
    const float* __restrict__ x, const float* __restrict__ mean, const float* __restrict__ rs,
    float* __restrict__ out)
{
    int t = threadIdx.x;
    long orow = (long)blockIdx.x*8 + (t>>5);
    int c0 = (t&31)*8;
    int b = (int)(orow / NNODES);
    int n = (int)(orow - (long)b*NNODES);
    s8v v = *(const s8v*)(Ybf + ((long)n*4 + b)*256 + c0);
    float4 m0 = *(const float4*)(mean + b*256 + c0);
    float4 m1 = *(const float4*)(mean + b*256 + c0 + 4);
    float4 r0 = *(const float4*)(rs + b*256 + c0);
    float4 r1 = *(const float4*)(rs + b*256 + c0 + 4);
    float mm[8] = {m0.x,m0.y,m0.z,m0.w,m1.x,m1.y,m1.z,m1.w};
    float rr[8] = {r0.x,r0.y,r0.z,r0.w,r1.x,r1.y,r1.z,r1.w};
    const float* xp = x + orow*256 + c0;
    float* op = out + orow*256 + c0;
    #pragma unroll
    for (int j = 0; j < 8; ++j)
        op[j] = fmaxf((b2f((ushort)v[j]) - mm[j])*rr[j], 0.f) + xp[j];
}

extern "C" void kernel_launch(void* const* d_in, const int* in_sizes, int n_in,
                              void* d_out, int out_size, void* d_ws, size_t ws_size,
                              hipStream_t stream)
{
    const float* x  = (const float*)d_in[0];
    const int*   ei = (const int*)d_in[1];
    const float* ew = (const float*)d_in[2];
    const float* W1 = (const float*)d_in[3];
    const float* W2 = (const float*)d_in[5];
    const float* W3 = (const float*)d_in[7];
    const int* row = ei;
    const int* col = ei + NE;

    char* p = (char*)d_ws;
    size_t used = 0;
    auto alloc = [&](size_t bytes) -> void* {
        void* r = p + used;
        used += (bytes + 1023) & ~(size_t)1023;
        return r;
    };
    float* deg   = (float*)alloc((size_t)3*NNODES*4);     // deg | cnt | fill (zeroed)
    int*   cnt   = (int*)(deg + NNODES);
    int*   fillc = (int*)(deg + 2*NNODES);
    float* dinv  = (float*)alloc((size_t)NNODES*4);
    int*   rowptr= (int*)alloc((size_t)(NNODES+1)*4);
    int*   ecol  = (int*)alloc((size_t)NE*4);
    float* ea    = (float*)alloc((size_t)NE*4);
    float* mrs   = (float*)alloc((size_t)3*2*1024*4);     // per layer: mean[1024] | rs[1024]
    ushort* Bp1  = (ushort*)alloc((size_t)256*192*2);
    ushort* Bp2  = (ushort*)alloc((size_t)64*192*2);
    ushort* Bp3  = (ushort*)alloc((size_t)192*256*2);
    ushort* Za   = (ushort*)alloc((size_t)MTOT*64*2);
    ushort* Zb   = (ushort*)alloc((size_t)MTOT*64*2);
    ushort* Zc   = (ushort*)alloc((size_t)MTOT*64*2);
    ushort* Zd   = (ushort*)alloc((size_t)MTOT*64*2);
    float* Pbig  = (float*)alloc((size_t)6144*512*4);     // prop stats partials (12.6 MB)
    float* PPa   = (float*)alloc((size_t)256*2048*4);     // 2 MB
    float* PPb   = (float*)alloc((size_t)16*2048*4);      // 128 KB
    ushort* Ybf  = (ushort*)alloc((size_t)MTOT*256*2);    // 100 MB
    if (ws_size < used) return;

    float* mean1 = mrs;          float* rs1 = mrs + 1024;
    float* mean2 = mrs + 2048;   float* rs2 = mrs + 3072;
    float* mean3 = mrs + 4096;   float* rs3 = mrs + 5120;
    float* Pst3  = (float*)d_out;   // gemm3 stats partials scratch (3072x2048 fp32 = 25 MB < 201 MB),
                                    // consumed by reductions BEFORE k_final overwrites d_out

    // ---- setup ----
    hipMemsetAsync(deg, 0, (size_t)3*NNODES*4, stream);
    k_deg_cnt<<<NE/256, 256, 0, stream>>>(row, ew, deg, cnt);
    k_dinv<<<NNODES/256, 256, 0, stream>>>(deg, dinv);
    k_scan<<<1, 1024, 0, stream>>>(cnt, rowptr);
    k_fill<<<NE/256, 256, 0, stream>>>(row, col, ew, dinv, rowptr, fillc, ecol, ea);
    k_packB<<<24, 256, 0, stream>>>(W1, 256, 12, 256, 0, Bp1);
    k_packB<<<6, 256, 0, stream>>>(W2, 64, 12, 64, 0, Bp2);
    k_packB<<<24, 256, 0, stream>>>(W3, 64, 16, 192, 1, Bp3);

    // ---- layer 1: 256 -> 64 (Za=y0, Zb=u1, Zc=u2, node-major) ----
    k_gemm1<<<NNODES/16, 256, 0, stream>>>(x, Bp1, Za, Zb, Zc);
    k_prop<<<NNODES/8, 256, 0, stream>>>(rowptr, ecol, ea, Zc, Zb, 1.f, Zb, -2.f, nullptr);      // z = u1 - 2S(u2)
    k_prop<<<NNODES/8, 256, 0, stream>>>(rowptr, ecol, ea, Zb, Za, 1.f, Za, -1.f, Pbig);         // y = y0 - S(z) + stats
    k_redgen<<<dim3(2,512), 256, 0, stream>>>(Pbig, PPa, 512, 12);
    k_redgen<<<dim3(2,32), 256, 0, stream>>>(PPa, PPb, 512, 16);
    k_redfin<<<1, 256, 0, stream>>>(PPb, 512, 32, 64, mean1, rs1);
    k_normrelu<<<MTOT*64/2048, 256, 0, stream>>>(Za, mean1, rs1, Zc);                            // X2 = Zc

    // ---- layer 2: 64 -> 64 ----
    k_gemm2<<<MTOT/64, 256, 0, stream>>>(Zc, Bp2, Za, Zb, Zd);
    k_prop<<<NNODES/8, 256, 0, stream>>>(rowptr, ecol, ea, Zd, Zb, 1.f, Zb, -2.f, nullptr);
    k_prop<<<NNODES/8, 256, 0, stream>>>(rowptr, ecol, ea, Zb, Za, 1.f, Za, -1.f, Pbig);
    k_redgen<<<dim3(2,512), 256, 0, stream>>>(Pbig, PPa, 512, 12);
    k_redgen<<<dim3(2,32), 256, 0, stream>>>(PPa, PPb, 512, 16);
    k_redfin<<<1, 256, 0, stream>>>(PPb, 512, 32, 64, mean2, rs2);
    k_normrelu<<<MTOT*64/2048, 256, 0, stream>>>(Za, mean2, rs2, Zc);                            // X3 = Zc

    // ---- layer 3: 64 -> 256 (propagate in 64-dim input space) ----
    k_prop<<<NNODES/8, 256, 0, stream>>>(rowptr, ecol, ea, Zc, (const ushort*)nullptr, 0.f, Za, -1.f, nullptr); // T1
    k_prop<<<NNODES/8, 256, 0, stream>>>(rowptr, ecol, ea, Za, Zc, -1.f, Zb, -2.f, nullptr);                    // T2
    k_gemm3<<<MTOT/64, 256, 0, stream>>>(Zc, Za, Zb, Bp3, Ybf, Pst3);
    k_redgen<<<dim3(8,256), 256, 0, stream>>>(Pst3, PPa, 2048, 12);
    k_redgen<<<dim3(8,16), 256, 0, stream>>>(PPa, PPb, 2048, 16);
    k_redfin<<<4, 256, 0, stream>>>(PPb, 2048, 16, 256, mean3, rs3);
    k_final<<<MTOT/8, 256, 0, stream>>>(Ybf, x, mean3, rs3, (float*)d_out);
}